// Round 1
// baseline (675.009 us; speedup 1.0000x reference)
//
#include <hip/hip_runtime.h>
#include <cstdint>
#include <cstddef>

#define B_  16
#define C_  128
#define N_  2048
#define K_  4
#define O_  64
#define OR_ 128
#define C2_ 256   // 2*C
#define ED_ 320   // 2*C + O
#define NM_ 4096  // N*R

// ---------------- Kernel 1: xx[b*N+n] = sum_c x[b,c,n]^2 ----------------
__global__ __launch_bounds__(256) void xx_kernel(const float* __restrict__ x,
                                                 float* __restrict__ xx) {
  int g = blockIdx.x * 256 + threadIdx.x;      // 0..B*N-1
  int b = g >> 11;
  int n = g & (N_ - 1);
  const float* xp = x + (size_t)b * C_ * N_ + n;
  float s = 0.f;
#pragma unroll 8
  for (int c = 0; c < C_; ++c) {
    float v = xp[(size_t)c * N_];
    s += v * v;
  }
  xx[g] = s;
}

// ---------------- Kernel 2: top-4 nearest (incl self) per point ----------------
// dist ranking key: xx[m] - 2*dot(q,m)   (xx[q] constant per query row)
__global__ __launch_bounds__(256) void knn_kernel(const float* __restrict__ x,
                                                  const float* __restrict__ xx,
                                                  int* __restrict__ knn_out) {
  __shared__ __align__(16) float qT[C_ * 64];  // [c][q] 32KB
  __shared__ __align__(16) float mT[C_ * 64];  // [c][m] 32KB
  const int b = blockIdx.y;
  const int q0 = blockIdx.x * 64;
  const int t = threadIdx.x;
  const float* xb = x + (size_t)b * C_ * N_;
  const float* xxb = xx + b * N_;

  for (int i = t; i < C_ * 64; i += 256) {
    int c = i >> 6, q = i & 63;
    qT[i] = xb[(size_t)c * N_ + q0 + q];
  }

  const int tq = t & 15;   // query group: queries tq*4 .. tq*4+3
  const int tm = t >> 4;   // m group:     m_local tm*4 .. tm*4+3
  float bd[4][4];
  int bi[4][4];
#pragma unroll
  for (int a = 0; a < 4; ++a)
#pragma unroll
    for (int s = 0; s < 4; ++s) { bd[a][s] = 1e30f; bi[a][s] = 0; }

  for (int m0 = 0; m0 < N_; m0 += 64) {
    __syncthreads();
    for (int i = t; i < C_ * 64; i += 256) {
      int c = i >> 6, m = i & 63;
      mT[i] = xb[(size_t)c * N_ + m0 + m];
    }
    __syncthreads();

    float acc[4][4];
#pragma unroll
    for (int a = 0; a < 4; ++a)
#pragma unroll
      for (int j = 0; j < 4; ++j) acc[a][j] = 0.f;

#pragma unroll 4
    for (int c = 0; c < C_; ++c) {
      float4 qv = *(const float4*)&qT[c * 64 + tq * 4];
      float4 mv = *(const float4*)&mT[c * 64 + tm * 4];
      float qa[4] = {qv.x, qv.y, qv.z, qv.w};
      float ma[4] = {mv.x, mv.y, mv.z, mv.w};
#pragma unroll
      for (int a = 0; a < 4; ++a)
#pragma unroll
        for (int j = 0; j < 4; ++j) acc[a][j] += qa[a] * ma[j];
    }

#pragma unroll
    for (int j = 0; j < 4; ++j) {
      float xm = xxb[m0 + tm * 4 + j];
      int id = m0 + tm * 4 + j;
#pragma unroll
      for (int a = 0; a < 4; ++a) {
        float d = xm - 2.f * acc[a][j];
        if (d < bd[a][3]) {
          bd[a][3] = d; bi[a][3] = id;
#pragma unroll
          for (int s = 3; s > 0; --s) {
            if (bd[a][s] < bd[a][s - 1]) {
              float td = bd[a][s]; bd[a][s] = bd[a][s - 1]; bd[a][s - 1] = td;
              int ti = bi[a][s]; bi[a][s] = bi[a][s - 1]; bi[a][s - 1] = ti;
            }
          }
        }
      }
    }
  }

  // merge: 16 threads (tm) hold top-4 candidates for each query
  __syncthreads();
  float* cd = qT;           // [64 q][64 cand]
  int* ci = (int*)mT;
#pragma unroll
  for (int a = 0; a < 4; ++a) {
    int q = tq * 4 + a;
#pragma unroll
    for (int s = 0; s < 4; ++s) {
      cd[q * 64 + tm * 4 + s] = bd[a][s];
      ci[q * 64 + tm * 4 + s] = bi[a][s];
    }
  }
  __syncthreads();
  if (t < 64) {
    float fd[4]; int fi[4];
#pragma unroll
    for (int s = 0; s < 4; ++s) { fd[s] = 1e30f; fi[s] = 0; }
    for (int j = 0; j < 64; ++j) {
      float d = cd[t * 64 + j];
      int id = ci[t * 64 + j];
      if (d < fd[3]) {
        fd[3] = d; fi[3] = id;
#pragma unroll
        for (int s = 3; s > 0; --s) {
          if (fd[s] < fd[s - 1]) {
            float td = fd[s]; fd[s] = fd[s - 1]; fd[s - 1] = td;
            int ti = fi[s]; fi[s] = fi[s - 1]; fi[s - 1] = ti;
          }
        }
      }
    }
#pragma unroll
    for (int s = 0; s < 4; ++s)
      knn_out[(b * N_ + q0 + t) * K_ + s] = fi[s];
  }
}

// ---------------- Kernel 3: gather + e1 + e2 + e3 + max over k ----------------
// Block: 16 n's  -> 64 (n,k) columns, col = nl*4 + k
__global__ __launch_bounds__(256) void fused_kernel(
    const float* __restrict__ x, const int* __restrict__ knn_idx,
    const float* __restrict__ w1, const float* __restrict__ b1,
    const float* __restrict__ w2, const float* __restrict__ b2,
    const float* __restrict__ w3, const float* __restrict__ b3,
    float* __restrict__ out) {
  __shared__ __align__(16) float fL[C2_ * 64];   // 64KB  ief: [c][col]
  __shared__ __align__(16) float e1L[O_ * 64];   // 16KB  relu(e1): [o][col]  (later reused for e3max)
  __shared__ __align__(16) float e2L[OR_ * 64];  // 32KB  relu(e2): [j][col]
  __shared__ int nidx[64];

  const int b = blockIdx.y;
  const int n0 = blockIdx.x * 16;
  const int t = threadIdx.x;
  const float* xb = x + (size_t)b * C_ * N_;

  if (t < 64) nidx[t] = knn_idx[(b * N_ + n0 + (t >> 2)) * K_ + (t & 3)];
  __syncthreads();

  for (int i = t; i < C_ * 64; i += 256) {
    int c = i >> 6, col = i & 63;
    fL[i] = xb[(size_t)c * N_ + n0 + (col >> 2)];            // center rows 0..127
    fL[C_ * 64 + i] = xb[(size_t)c * N_ + nidx[col]];        // neighbor rows 128..255
  }
  __syncthreads();

  const int ct = t & 15;   // col group (4 cols)
  const int rt = t >> 4;   // row group

  // ---- phase 1: e1 = w1 @ f + b1 ; store relu(e1) ----
  {
    float acc[4][4];
#pragma unroll
    for (int a = 0; a < 4; ++a) {
      float bv = b1[rt * 4 + a];
#pragma unroll
      for (int j = 0; j < 4; ++j) acc[a][j] = bv;
    }
    for (int c0 = 0; c0 < C2_; c0 += 8) {
      float w[4][8];
#pragma unroll
      for (int a = 0; a < 4; ++a) {
        float4 wa = *(const float4*)&w1[(rt * 4 + a) * C2_ + c0];
        float4 wb = *(const float4*)&w1[(rt * 4 + a) * C2_ + c0 + 4];
        w[a][0] = wa.x; w[a][1] = wa.y; w[a][2] = wa.z; w[a][3] = wa.w;
        w[a][4] = wb.x; w[a][5] = wb.y; w[a][6] = wb.z; w[a][7] = wb.w;
      }
#pragma unroll
      for (int cc = 0; cc < 8; ++cc) {
        float4 fv = *(const float4*)&fL[(c0 + cc) * 64 + ct * 4];
        float fa[4] = {fv.x, fv.y, fv.z, fv.w};
#pragma unroll
        for (int a = 0; a < 4; ++a)
#pragma unroll
          for (int j = 0; j < 4; ++j) acc[a][j] += w[a][cc] * fa[j];
      }
    }
#pragma unroll
    for (int a = 0; a < 4; ++a) {
      float4 st;
      st.x = fmaxf(acc[a][0], 0.f); st.y = fmaxf(acc[a][1], 0.f);
      st.z = fmaxf(acc[a][2], 0.f); st.w = fmaxf(acc[a][3], 0.f);
      *(float4*)&e1L[(rt * 4 + a) * 64 + ct * 4] = st;
    }
  }
  __syncthreads();

  // ---- phase 2: e2 = relu(w2 @ [relu(e1); relu(f)] + b2) ----
  {
    float acc[8][4];
#pragma unroll
    for (int a = 0; a < 8; ++a) {
      float bv = b2[rt * 8 + a];
#pragma unroll
      for (int j = 0; j < 4; ++j) acc[a][j] = bv;
    }
    // part A: channels 0..63 from relu(e1)
    for (int r0 = 0; r0 < O_; r0 += 8) {
      float w[8][8];
#pragma unroll
      for (int a = 0; a < 8; ++a) {
        float4 wa = *(const float4*)&w2[(rt * 8 + a) * ED_ + r0];
        float4 wb = *(const float4*)&w2[(rt * 8 + a) * ED_ + r0 + 4];
        w[a][0] = wa.x; w[a][1] = wa.y; w[a][2] = wa.z; w[a][3] = wa.w;
        w[a][4] = wb.x; w[a][5] = wb.y; w[a][6] = wb.z; w[a][7] = wb.w;
      }
#pragma unroll
      for (int rr = 0; rr < 8; ++rr) {
        float4 ev = *(const float4*)&e1L[(r0 + rr) * 64 + ct * 4];
        float ea[4] = {ev.x, ev.y, ev.z, ev.w};
#pragma unroll
        for (int a = 0; a < 8; ++a)
#pragma unroll
          for (int j = 0; j < 4; ++j) acc[a][j] += w[a][rr] * ea[j];
      }
    }
    // part B: channels 64..319 from relu(f)
    for (int c0 = 0; c0 < C2_; c0 += 8) {
      float w[8][8];
#pragma unroll
      for (int a = 0; a < 8; ++a) {
        float4 wa = *(const float4*)&w2[(rt * 8 + a) * ED_ + O_ + c0];
        float4 wb = *(const float4*)&w2[(rt * 8 + a) * ED_ + O_ + c0 + 4];
        w[a][0] = wa.x; w[a][1] = wa.y; w[a][2] = wa.z; w[a][3] = wa.w;
        w[a][4] = wb.x; w[a][5] = wb.y; w[a][6] = wb.z; w[a][7] = wb.w;
      }
#pragma unroll
      for (int cc = 0; cc < 8; ++cc) {
        float4 fv = *(const float4*)&fL[(c0 + cc) * 64 + ct * 4];
        float fa[4] = {fmaxf(fv.x, 0.f), fmaxf(fv.y, 0.f),
                       fmaxf(fv.z, 0.f), fmaxf(fv.w, 0.f)};
#pragma unroll
        for (int a = 0; a < 8; ++a)
#pragma unroll
          for (int j = 0; j < 4; ++j) acc[a][j] += w[a][cc] * fa[j];
      }
    }
#pragma unroll
    for (int a = 0; a < 8; ++a) {
      float4 st;
      st.x = fmaxf(acc[a][0], 0.f); st.y = fmaxf(acc[a][1], 0.f);
      st.z = fmaxf(acc[a][2], 0.f); st.w = fmaxf(acc[a][3], 0.f);
      *(float4*)&e2L[(rt * 8 + a) * 64 + ct * 4] = st;
    }
  }
  __syncthreads();

  // ---- phase 3: e3[o, r, nl, k] = w3 @ e2[r*64.., col] ; max over k ----
  float* o3L = e1L;  // reuse as [64 o][32 sub], sub = nl*2 + r
  {
#pragma unroll
    for (int ui = 0; ui < 2; ++ui) {
      const int r = ui;
      const int nl = ct;
      float acc[4][4];  // [o][k]
#pragma unroll
      for (int a = 0; a < 4; ++a)
#pragma unroll
        for (int k = 0; k < 4; ++k) acc[a][k] = 0.f;
      for (int p0 = 0; p0 < O_; p0 += 8) {
        float w[4][8];
#pragma unroll
        for (int a = 0; a < 4; ++a) {
          float4 wa = *(const float4*)&w3[(rt * 4 + a) * O_ + p0];
          float4 wb = *(const float4*)&w3[(rt * 4 + a) * O_ + p0 + 4];
          w[a][0] = wa.x; w[a][1] = wa.y; w[a][2] = wa.z; w[a][3] = wa.w;
          w[a][4] = wb.x; w[a][5] = wb.y; w[a][6] = wb.z; w[a][7] = wb.w;
        }
#pragma unroll
        for (int pp = 0; pp < 8; ++pp) {
          float4 ev = *(const float4*)&e2L[(r * O_ + p0 + pp) * 64 + nl * 4];
          float ea[4] = {ev.x, ev.y, ev.z, ev.w};
#pragma unroll
          for (int a = 0; a < 4; ++a)
#pragma unroll
            for (int k = 0; k < 4; ++k) acc[a][k] += w[a][pp] * ea[k];
        }
      }
#pragma unroll
      for (int a = 0; a < 4; ++a) {
        float best = fmaxf(fmaxf(acc[a][0], acc[a][1]), fmaxf(acc[a][2], acc[a][3]));
        o3L[(rt * 4 + a) * 32 + nl * 2 + r] = best + b3[rt * 4 + a];
      }
    }
  }
  __syncthreads();
  // coalesced write: per o, 32 contiguous m's
  for (int i = t; i < O_ * 32; i += 256) {
    int o = i >> 5, sub = i & 31;
    out[((size_t)b * O_ + o) * NM_ + n0 * 2 + sub] = o3L[i];
  }
}

extern "C" void kernel_launch(void* const* d_in, const int* in_sizes, int n_in,
                              void* d_out, int out_size, void* d_ws, size_t ws_size,
                              hipStream_t stream) {
  const float* x = (const float*)d_in[0];
  const float* w1 = (const float*)d_in[1];
  const float* b1 = (const float*)d_in[2];
  const float* w2 = (const float*)d_in[3];
  const float* b2 = (const float*)d_in[4];
  const float* w3 = (const float*)d_in[5];
  const float* b3 = (const float*)d_in[6];
  float* out = (float*)d_out;

  float* xx = (float*)d_ws;                                    // B*N floats = 128KB
  int* knn = (int*)((char*)d_ws + (size_t)B_ * N_ * sizeof(float));  // B*N*K ints = 512KB

  hipLaunchKernelGGL(xx_kernel, dim3((B_ * N_) / 256), dim3(256), 0, stream, x, xx);
  hipLaunchKernelGGL(knn_kernel, dim3(N_ / 64, B_), dim3(256), 0, stream, x, xx, knn);
  hipLaunchKernelGGL(fused_kernel, dim3(N_ / 16, B_), dim3(256), 0, stream,
                     x, knn, w1, b1, w2, b2, w3, b3, out);
}

// Round 2
// 455.782 us; speedup vs baseline: 1.4810x; 1.4810x over previous
//
#include <hip/hip_runtime.h>
#include <cstdint>
#include <cstddef>

#define B_  16
#define C_  128
#define N_  2048
#define K_  4
#define O_  64
#define C2_ 256   // 2*C
#define ED_ 320   // 2*C + O
#define NM_ 4096  // N*R

typedef float  f32x4  __attribute__((ext_vector_type(4)));
typedef short  s16x8  __attribute__((ext_vector_type(8)));
typedef __bf16 bf16x4 __attribute__((ext_vector_type(4)));
typedef __bf16 bf16x8 __attribute__((ext_vector_type(8)));

__device__ __forceinline__ s16x8 ldw_bf16(const float* __restrict__ p) {
  float4 a = *(const float4*)p;
  float4 c = *(const float4*)(p + 4);
  bf16x8 r;
  r[0] = (__bf16)a.x; r[1] = (__bf16)a.y; r[2] = (__bf16)a.z; r[3] = (__bf16)a.w;
  r[4] = (__bf16)c.x; r[5] = (__bf16)c.y; r[6] = (__bf16)c.z; r[7] = (__bf16)c.w;
  return __builtin_bit_cast(s16x8, r);
}

// ---------------- Kernel 1: xx[b*N+n] = sum_c x[b,c,n]^2 ----------------
__global__ __launch_bounds__(256) void xx_kernel(const float* __restrict__ x,
                                                 float* __restrict__ xx) {
  int g = blockIdx.x * 256 + threadIdx.x;
  int b = g >> 11;
  int n = g & (N_ - 1);
  const float* xp = x + (size_t)b * C_ * N_ + n;
  float s = 0.f;
#pragma unroll 8
  for (int c = 0; c < C_; ++c) {
    float v = xp[(size_t)c * N_];
    s += v * v;
  }
  xx[g] = s;
}

// ---------------- Kernel 2: top-4 nearest (incl self), exact fp32 ----------------
__global__ __launch_bounds__(256) void knn_kernel(const float* __restrict__ x,
                                                  const float* __restrict__ xx,
                                                  int* __restrict__ knn_out) {
  __shared__ __align__(16) float qT[C_ * 64];
  __shared__ __align__(16) float mT[C_ * 64];
  const int b = blockIdx.y;
  const int q0 = blockIdx.x * 64;
  const int t = threadIdx.x;
  const float* xb = x + (size_t)b * C_ * N_;
  const float* xxb = xx + b * N_;

  for (int i = t; i < C_ * 64; i += 256) {
    int c = i >> 6, q = i & 63;
    qT[i] = xb[(size_t)c * N_ + q0 + q];
  }

  const int tq = t & 15;
  const int tm = t >> 4;
  float bd[4][4];
  int bi[4][4];
#pragma unroll
  for (int a = 0; a < 4; ++a)
#pragma unroll
    for (int s = 0; s < 4; ++s) { bd[a][s] = 1e30f; bi[a][s] = 0; }

  for (int m0 = 0; m0 < N_; m0 += 64) {
    __syncthreads();
    for (int i = t; i < C_ * 64; i += 256) {
      int c = i >> 6, m = i & 63;
      mT[i] = xb[(size_t)c * N_ + m0 + m];
    }
    __syncthreads();

    float acc[4][4];
#pragma unroll
    for (int a = 0; a < 4; ++a)
#pragma unroll
      for (int j = 0; j < 4; ++j) acc[a][j] = 0.f;

#pragma unroll 4
    for (int c = 0; c < C_; ++c) {
      float4 qv = *(const float4*)&qT[c * 64 + tq * 4];
      float4 mv = *(const float4*)&mT[c * 64 + tm * 4];
      float qa[4] = {qv.x, qv.y, qv.z, qv.w};
      float ma[4] = {mv.x, mv.y, mv.z, mv.w};
#pragma unroll
      for (int a = 0; a < 4; ++a)
#pragma unroll
        for (int j = 0; j < 4; ++j) acc[a][j] += qa[a] * ma[j];
    }

#pragma unroll
    for (int j = 0; j < 4; ++j) {
      float xm = xxb[m0 + tm * 4 + j];
      int id = m0 + tm * 4 + j;
#pragma unroll
      for (int a = 0; a < 4; ++a) {
        float d = xm - 2.f * acc[a][j];
        if (d < bd[a][3]) {
          bd[a][3] = d; bi[a][3] = id;
#pragma unroll
          for (int s = 3; s > 0; --s) {
            if (bd[a][s] < bd[a][s - 1]) {
              float td = bd[a][s]; bd[a][s] = bd[a][s - 1]; bd[a][s - 1] = td;
              int ti = bi[a][s]; bi[a][s] = bi[a][s - 1]; bi[a][s - 1] = ti;
            }
          }
        }
      }
    }
  }

  __syncthreads();
  float* cd = qT;
  int* ci = (int*)mT;
#pragma unroll
  for (int a = 0; a < 4; ++a) {
    int q = tq * 4 + a;
#pragma unroll
    for (int s = 0; s < 4; ++s) {
      cd[q * 64 + tm * 4 + s] = bd[a][s];
      ci[q * 64 + tm * 4 + s] = bi[a][s];
    }
  }
  __syncthreads();
  if (t < 64) {
    float fd[4]; int fi[4];
#pragma unroll
    for (int s = 0; s < 4; ++s) { fd[s] = 1e30f; fi[s] = 0; }
    for (int j = 0; j < 64; ++j) {
      float d = cd[t * 64 + j];
      int id = ci[t * 64 + j];
      if (d < fd[3]) {
        fd[3] = d; fi[3] = id;
#pragma unroll
        for (int s = 3; s > 0; --s) {
          if (fd[s] < fd[s - 1]) {
            float td = fd[s]; fd[s] = fd[s - 1]; fd[s - 1] = td;
            int ti = fi[s]; fi[s] = fi[s - 1]; fi[s - 1] = ti;
          }
        }
      }
    }
#pragma unroll
    for (int s = 0; s < 4; ++s)
      knn_out[(b * N_ + q0 + t) * K_ + s] = fi[s];
  }
}

// ---------------- Kernel 3: gather + e1 + e2 + e3 + max, bf16 MFMA ----------------
// Block: 16 n's -> 64 (n,k) cols. 4 waves. Activations col-major in LDS.
__global__ __launch_bounds__(256) void fused_mfma(
    const float* __restrict__ x, const int* __restrict__ knn_idx,
    const float* __restrict__ w1, const float* __restrict__ b1,
    const float* __restrict__ w2, const float* __restrict__ b2,
    const float* __restrict__ w3, const float* __restrict__ b3,
    float* __restrict__ out) {
  __shared__ __align__(16) __bf16 cT [16][136];   // raw center   [n][k0..127]
  __shared__ __align__(16) __bf16 cTr[16][136];   // relu center
  __shared__ __align__(16) __bf16 nT [64][136];   // raw neighbor [col][k0..127]
  __shared__ __align__(16) __bf16 nTr[64][136];   // relu neighbor
  __shared__ __align__(16) __bf16 e1T[64][72];    // relu(e1)     [col][o]
  __shared__ __align__(16) __bf16 e2T[64][136];   // relu(e2)     [col][j 0..127]
  __shared__ __align__(16) float  oSt[64][36];    // e3 max       [o][mloc]
  __shared__ int nidx[64];

  const int b  = blockIdx.y;
  const int n0 = blockIdx.x * 16;
  const int t  = threadIdx.x;
  const float* xb = x + (size_t)b * C_ * N_;

  if (t < 64) nidx[t] = knn_idx[(b * N_ + n0 + (t >> 2)) * K_ + (t & 3)];
  __syncthreads();

  // ---- stage center (16 n x 16 chunks of 8 rows) ----
  {
    int n = t >> 4, ch = t & 15;
    const float* src = xb + (size_t)(ch * 8) * N_ + n0 + n;
    bf16x8 raw, rel;
#pragma unroll
    for (int j = 0; j < 8; ++j) {
      float v = src[(size_t)j * N_];
      raw[j] = (__bf16)v;
      rel[j] = (__bf16)fmaxf(v, 0.f);
    }
    *(bf16x8*)&cT [n][ch * 8] = raw;
    *(bf16x8*)&cTr[n][ch * 8] = rel;
  }
  // ---- stage neighbors (64 cols x 16 chunks) ----
#pragma unroll
  for (int it = 0; it < 4; ++it) {
    int u = t + it * 256;
    int col = u >> 4, ch = u & 15;
    const float* src = xb + (size_t)(ch * 8) * N_ + nidx[col];
    bf16x8 raw, rel;
#pragma unroll
    for (int j = 0; j < 8; ++j) {
      float v = src[(size_t)j * N_];
      raw[j] = (__bf16)v;
      rel[j] = (__bf16)fmaxf(v, 0.f);
    }
    *(bf16x8*)&nT [col][ch * 8] = raw;
    *(bf16x8*)&nTr[col][ch * 8] = rel;
  }
  __syncthreads();

  const int lq = t & 15;         // frag row/col lane index
  const int lh = (t >> 4) & 3;   // frag k-block
  const int wv = t >> 6;         // wave id

  // ---- phase 1: e1 = relu(w1 @ f + b1), K=256 ----
  {
    const float* w1r = w1 + (size_t)(wv * 16 + lq) * C2_;
    f32x4 acc[4] = {{0,0,0,0},{0,0,0,0},{0,0,0,0},{0,0,0,0}};
#pragma unroll
    for (int ks = 0; ks < 8; ++ks) {
      s16x8 a = ldw_bf16(w1r + ks * 32 + lh * 8);
#pragma unroll
      for (int cg = 0; cg < 4; ++cg) {
        const __bf16* bp = (ks < 4)
            ? &cT[cg * 4 + (lq >> 2)][ks * 32 + lh * 8]
            : &nT[cg * 16 + lq][(ks - 4) * 32 + lh * 8];
        acc[cg] = __builtin_amdgcn_mfma_f32_16x16x32_bf16(
            a, *(const s16x8*)bp, acc[cg], 0, 0, 0);
      }
    }
#pragma unroll
    for (int cg = 0; cg < 4; ++cg) {
      bf16x4 st;
#pragma unroll
      for (int r = 0; r < 4; ++r) {
        float v = acc[cg][r] + b1[wv * 16 + lh * 4 + r];
        st[r] = (__bf16)fmaxf(v, 0.f);
      }
      *(bf16x4*)&e1T[cg * 16 + lq][wv * 16 + lh * 4] = st;
    }
  }
  __syncthreads();

  // ---- phase 2: e2 = relu(w2 @ [relu(e1); relu(f)] + b2), K=320 ----
  {
    const float* w2r0 = w2 + (size_t)(wv * 32 + lq) * ED_;
    const float* w2r1 = w2r0 + (size_t)16 * ED_;
    f32x4 acc[2][4];
#pragma unroll
    for (int ro = 0; ro < 2; ++ro)
#pragma unroll
      for (int cg = 0; cg < 4; ++cg) acc[ro][cg] = (f32x4){0, 0, 0, 0};
#pragma unroll
    for (int ks = 0; ks < 10; ++ks) {
      s16x8 a0 = ldw_bf16(w2r0 + ks * 32 + lh * 8);
      s16x8 a1 = ldw_bf16(w2r1 + ks * 32 + lh * 8);
#pragma unroll
      for (int cg = 0; cg < 4; ++cg) {
        const __bf16* bp;
        if (ks < 2)      bp = &e1T[cg * 16 + lq][ks * 32 + lh * 8];
        else if (ks < 6) bp = &cTr[cg * 4 + (lq >> 2)][(ks - 2) * 32 + lh * 8];
        else             bp = &nTr[cg * 16 + lq][(ks - 6) * 32 + lh * 8];
        s16x8 bf = *(const s16x8*)bp;
        acc[0][cg] = __builtin_amdgcn_mfma_f32_16x16x32_bf16(a0, bf, acc[0][cg], 0, 0, 0);
        acc[1][cg] = __builtin_amdgcn_mfma_f32_16x16x32_bf16(a1, bf, acc[1][cg], 0, 0, 0);
      }
    }
#pragma unroll
    for (int ro = 0; ro < 2; ++ro)
#pragma unroll
      for (int cg = 0; cg < 4; ++cg) {
        bf16x4 st;
#pragma unroll
        for (int r = 0; r < 4; ++r) {
          float v = acc[ro][cg][r] + b2[wv * 32 + ro * 16 + lh * 4 + r];
          st[r] = (__bf16)fmaxf(v, 0.f);
        }
        *(bf16x4*)&e2T[cg * 16 + lq][wv * 32 + ro * 16 + lh * 4] = st;
      }
  }
  __syncthreads();

  // ---- phase 3: e3 = w3 @ e2' (K=64), max over k, +b3 ----
  // col' = nl*8 + r*4 + k  (k fastest -> max over lanes lq^1, lq^2)
  {
    const float* w3r = w3 + (size_t)(wv * 16 + lq) * O_;
    s16x8 a0 = ldw_bf16(w3r + lh * 8);
    s16x8 a1 = ldw_bf16(w3r + 32 + lh * 8);
#pragma unroll
    for (int cg = 0; cg < 8; ++cg) {
      int col = cg * 16 + lq;
      int nl = col >> 3, rr = (col >> 2) & 1, kk = col & 3;
      const __bf16* base = &e2T[nl * 4 + kk][rr * 64];
      f32x4 acc = {0, 0, 0, 0};
      acc = __builtin_amdgcn_mfma_f32_16x16x32_bf16(a0, *(const s16x8*)(base + lh * 8),      acc, 0, 0, 0);
      acc = __builtin_amdgcn_mfma_f32_16x16x32_bf16(a1, *(const s16x8*)(base + 32 + lh * 8), acc, 0, 0, 0);
      float vv[4];
#pragma unroll
      for (int r = 0; r < 4; ++r) {
        float v = acc[r];
        v = fmaxf(v, __shfl_xor(v, 1));
        v = fmaxf(v, __shfl_xor(v, 2));
        vv[r] = v;
      }
      if ((lq & 3) == 0) {
        int mloc = col >> 2;
        int o = wv * 16 + lh * 4;
#pragma unroll
        for (int r = 0; r < 4; ++r) oSt[o + r][mloc] = vv[r] + b3[o + r];
      }
    }
  }
  __syncthreads();

  // ---- coalesced output write: 64 o-rows x 32 m ----
#pragma unroll
  for (int it = 0; it < 2; ++it) {
    int u = t + it * 256;
    int o = u >> 3, seg = u & 7;
    *(float4*)&out[((size_t)b * O_ + o) * NM_ + n0 * 2 + seg * 4] =
        *(const float4*)&oSt[o][seg * 4];
  }
}

extern "C" void kernel_launch(void* const* d_in, const int* in_sizes, int n_in,
                              void* d_out, int out_size, void* d_ws, size_t ws_size,
                              hipStream_t stream) {
  const float* x  = (const float*)d_in[0];
  const float* w1 = (const float*)d_in[1];
  const float* b1 = (const float*)d_in[2];
  const float* w2 = (const float*)d_in[3];
  const float* b2 = (const float*)d_in[4];
  const float* w3 = (const float*)d_in[5];
  const float* b3 = (const float*)d_in[6];
  float* out = (float*)d_out;

  float* xx = (float*)d_ws;
  int* knn = (int*)((char*)d_ws + (size_t)B_ * N_ * sizeof(float));

  hipLaunchKernelGGL(xx_kernel, dim3((B_ * N_) / 256), dim3(256), 0, stream, x, xx);
  hipLaunchKernelGGL(knn_kernel, dim3(N_ / 64, B_), dim3(256), 0, stream, x, xx, knn);
  hipLaunchKernelGGL(fused_mfma, dim3(N_ / 16, B_), dim3(256), 0, stream,
                     x, knn, w1, b1, w2, b2, w3, b3, out);
}

// Round 3
// 204.936 us; speedup vs baseline: 3.2938x; 2.2240x over previous
//
#include <hip/hip_runtime.h>
#include <cstdint>
#include <cstddef>

#define B_  16
#define C_  128
#define N_  2048
#define K_  4
#define O_  64
#define C2_ 256   // 2*C
#define ED_ 320   // 2*C + O
#define NM_ 4096  // N*R

typedef float  f32x4  __attribute__((ext_vector_type(4)));
typedef short  s16x8  __attribute__((ext_vector_type(8)));
typedef __bf16 bf16x4 __attribute__((ext_vector_type(4)));
typedef __bf16 bf16x8 __attribute__((ext_vector_type(8)));
typedef unsigned short u16;
typedef unsigned int   u32;

__device__ __forceinline__ s16x8 ldw_bf16(const float* __restrict__ p) {
  float4 a = *(const float4*)p;
  float4 c = *(const float4*)(p + 4);
  bf16x8 r;
  r[0] = (__bf16)a.x; r[1] = (__bf16)a.y; r[2] = (__bf16)a.z; r[3] = (__bf16)a.w;
  r[4] = (__bf16)c.x; r[5] = (__bf16)c.y; r[6] = (__bf16)c.z; r[7] = (__bf16)c.w;
  return __builtin_bit_cast(s16x8, r);
}

// relu on 2 packed bf16 in a u32: sign-bit -> zero the half
__device__ __forceinline__ u32 relu2(u32 u) {
  u32 s = u & 0x80008000u;
  u32 m = s - (s >> 15);
  return u & ~(m | s);
}

__device__ __forceinline__ void glds16(const void* g, void* l) {
  __builtin_amdgcn_global_load_lds(
      (const __attribute__((address_space(1))) u32*)g,
      (__attribute__((address_space(3))) u32*)l, 16, 0, 0);
}

// ============ prep: xx, xT32 (fp32 rows), xh (bf16 rows, XOR-swizzled) ============
__global__ __launch_bounds__(256) void prep_kernel(const float* __restrict__ x,
                                                   float* __restrict__ xT32,
                                                   u16* __restrict__ xh,
                                                   float* __restrict__ xx) {
  __shared__ __align__(16) float sx[C_][65];
  const int b = blockIdx.y, n0 = blockIdx.x * 64;
  const int t = threadIdx.x;
  const float* xb = x + (size_t)b * C_ * N_;
  for (int u = t; u < C_ * 16; u += 256) {
    int c = u >> 4, f4 = u & 15;
    float4 v = *(const float4*)&xb[(size_t)c * N_ + n0 + f4 * 4];
    sx[c][f4 * 4 + 0] = v.x; sx[c][f4 * 4 + 1] = v.y;
    sx[c][f4 * 4 + 2] = v.z; sx[c][f4 * 4 + 3] = v.w;
  }
  __syncthreads();
  if (t < 64) {
    float s = 0.f;
    for (int c = 0; c < C_; ++c) { float v = sx[c][t]; s = fmaf(v, v, s); }
    xx[b * N_ + n0 + t] = s;
  }
  for (int u = t; u < 64 * 16; u += 256) {
    int n = u >> 4, cb = u & 15;
    float vv[8]; s16x8 hv;
#pragma unroll
    for (int j = 0; j < 8; ++j) {
      float v = sx[cb * 8 + j][n];
      vv[j] = v;
      hv[j] = (short)__builtin_bit_cast(u16, (__bf16)v);
    }
    size_t ro = ((size_t)b * N_ + n0 + n) * C_;
    *(float4*)&xT32[ro + cb * 8]     = make_float4(vv[0], vv[1], vv[2], vv[3]);
    *(float4*)&xT32[ro + cb * 8 + 4] = make_float4(vv[4], vv[5], vv[6], vv[7]);
    int sc = cb ^ (n & 7);
    *(s16x8*)&xh[ro + sc * 8] = hv;
  }
}

// ============ knn stage 1: bf16 hh MFMA distances -> top-8 candidates/query ============
__global__ __launch_bounds__(256) void knn_mfma(const u16* __restrict__ xh,
                                                const float* __restrict__ xx,
                                                int* __restrict__ cand8) {
  __shared__ __align__(16) char smem[40960];  // 2x16KB staging; merge aliases 2x20KB
  const int b = blockIdx.y, q0 = blockIdx.x * 64;
  const int t = threadIdx.x;
  const int lane = t & 63, wv = t >> 6, lq = t & 15, lh = (t >> 4) & 3;
  const u16* xhb = xh + (size_t)b * N_ * C_;
  const float* xxb = xx + b * N_;

  // Q fragments (B-operand), held in registers for the whole kernel
  s16x8 qf[4][4];
#pragma unroll
  for (int qt = 0; qt < 4; ++qt)
#pragma unroll
    for (int ks = 0; ks < 4; ++ks) {
      int q = q0 + qt * 16 + lq;
      int ch = (ks * 4 + lh) ^ (q & 7);
      qf[qt][ks] = *(const s16x8*)&xhb[(size_t)q * C_ + ch * 8];
    }

  float bd[4][5]; int bi5[4][5];
#pragma unroll
  for (int qt = 0; qt < 4; ++qt)
#pragma unroll
    for (int s = 0; s < 5; ++s) { bd[qt][s] = 1e30f; bi5[qt][s] = 0; }

  // stage 64 m-rows (16KB contiguous, swizzle embedded in source)
  auto stage = [&](int bufi, int m0) {
    const char* s = (const char*)(xhb + (size_t)m0 * C_);
    char* d = smem + bufi * 16384;
#pragma unroll
    for (int c = 0; c < 4; ++c) {
      int off = (wv * 4 + c) * 1024;
      glds16(s + off + lane * 16, d + off);
    }
  };

  stage(0, 0);
  asm volatile("s_waitcnt vmcnt(0)");
  __syncthreads();

  for (int step = 0; step < 32; ++step) {
    const int cur = step & 1;
    if (step < 31) stage(cur ^ 1, (step + 1) * 64);
    const char* mb = smem + cur * 16384;
    f32x4 acc[4];
#pragma unroll
    for (int qt = 0; qt < 4; ++qt) acc[qt] = (f32x4){0.f, 0.f, 0.f, 0.f};
#pragma unroll
    for (int ks = 0; ks < 4; ++ks) {
      int row = wv * 16 + lq;
      int ch = (ks * 4 + lh) ^ (lq & 7);
      s16x8 mf = *(const s16x8*)(mb + row * 256 + ch * 16);
#pragma unroll
      for (int qt = 0; qt < 4; ++qt)
        acc[qt] = __builtin_amdgcn_mfma_f32_16x16x32_bf16(mf, qf[qt][ks], acc[qt], 0, 0, 0);
    }
    const int mrow = step * 64 + wv * 16 + lh * 4;
    float4 xm4 = *(const float4*)&xxb[mrow];
    float xma[4] = {xm4.x, xm4.y, xm4.z, xm4.w};
#pragma unroll
    for (int qt = 0; qt < 4; ++qt)
#pragma unroll
      for (int r = 0; r < 4; ++r) {
        float dd = fmaf(acc[qt][r], -2.f, xma[r]);
        int idm = mrow + r;
        if (dd < bd[qt][4]) {
          bd[qt][4] = dd; bi5[qt][4] = idm;
#pragma unroll
          for (int s = 4; s > 0; --s)
            if (bd[qt][s] < bd[qt][s - 1]) {
              float td = bd[qt][s]; bd[qt][s] = bd[qt][s - 1]; bd[qt][s - 1] = td;
              int ti = bi5[qt][s]; bi5[qt][s] = bi5[qt][s - 1]; bi5[qt][s - 1] = ti;
            }
        }
      }
    asm volatile("s_waitcnt vmcnt(0)");
    __syncthreads();
  }

  // merge: per local q, 16 units x 5 candidates
  float* cd = (float*)smem;
  int* ci = (int*)(smem + 20480);
  const int unit = wv * 4 + lh;
#pragma unroll
  for (int qt = 0; qt < 4; ++qt) {
    int ql = qt * 16 + lq;
#pragma unroll
    for (int s = 0; s < 5; ++s) {
      cd[ql * 80 + unit * 5 + s] = bd[qt][s];
      ci[ql * 80 + unit * 5 + s] = bi5[qt][s];
    }
  }
  __syncthreads();
  if (t < 64) {
    float fd[8]; int fi[8];
#pragma unroll
    for (int s = 0; s < 8; ++s) { fd[s] = 1e30f; fi[s] = 0; }
    for (int j = 0; j < 80; ++j) {
      float dd = cd[t * 80 + j]; int idm = ci[t * 80 + j];
      if (dd < fd[7]) {
        fd[7] = dd; fi[7] = idm;
#pragma unroll
        for (int s = 7; s > 0; --s)
          if (fd[s] < fd[s - 1]) {
            float td = fd[s]; fd[s] = fd[s - 1]; fd[s - 1] = td;
            int ti = fi[s]; fi[s] = fi[s - 1]; fi[s - 1] = ti;
          }
      }
    }
#pragma unroll
    for (int s = 0; s < 8; ++s)
      cand8[((size_t)b * N_ + q0 + t) * 8 + s] = fi[s];
  }
}

// ============ knn stage 2: exact fp32 rerank of 8 candidates -> top-4 ============
__global__ __launch_bounds__(256) void rerank_kernel(const float* __restrict__ xT32,
                                                     const float* __restrict__ xx,
                                                     const int* __restrict__ cand8,
                                                     int* __restrict__ knn_out) {
  __shared__ __align__(16) float sq[64][132];
  __shared__ float sd[64][8];
  __shared__ int   si[64][8];
  const int b = blockIdx.y, n0 = blockIdx.x * 64;
  const int t = threadIdx.x;
  const float* xb32 = xT32 + (size_t)b * N_ * C_;
  for (int u = t; u < 64 * 32; u += 256) {
    int n = u >> 5, seg = u & 31;
    *(float4*)&sq[n][seg * 4] = *(const float4*)&xb32[(size_t)(n0 + n) * C_ + seg * 4];
  }
  __syncthreads();
  const int ql = t >> 2, cs = t & 3;
#pragma unroll
  for (int cc = 0; cc < 2; ++cc) {
    int cslot = cs + cc * 4;
    int idx = cand8[((size_t)b * N_ + n0 + ql) * 8 + cslot];
    const float* mr = &xb32[(size_t)idx * C_];
    float a0 = 0.f, a1 = 0.f, a2 = 0.f, a3 = 0.f;
#pragma unroll 8
    for (int i = 0; i < 32; ++i) {
      float4 qv = *(const float4*)&sq[ql][i * 4];
      float4 mv = *(const float4*)&mr[i * 4];
      a0 = fmaf(qv.x, mv.x, a0); a1 = fmaf(qv.y, mv.y, a1);
      a2 = fmaf(qv.z, mv.z, a2); a3 = fmaf(qv.w, mv.w, a3);
    }
    float dot = (a0 + a1) + (a2 + a3);
    sd[ql][cslot] = xx[(size_t)b * N_ + idx] - 2.f * dot;
    si[ql][cslot] = idx;
  }
  __syncthreads();
  if (t < 64) {
    float dloc[8]; int iloc[8];
#pragma unroll
    for (int j = 0; j < 8; ++j) { dloc[j] = sd[t][j]; iloc[j] = si[t][j]; }
    u32 used = 0;
#pragma unroll
    for (int s = 0; s < 4; ++s) {
      float bdv = 1e30f; int bidx = 0x7fffffff; int bj = 0;
#pragma unroll
      for (int j = 0; j < 8; ++j) {
        if (!((used >> j) & 1)) {
          bool bet = (dloc[j] < bdv) || (dloc[j] == bdv && iloc[j] < bidx);
          if (bet) { bdv = dloc[j]; bidx = iloc[j]; bj = j; }
        }
      }
      used |= 1u << bj;
      knn_out[((size_t)b * N_ + n0 + t) * K_ + s] = bidx;
    }
  }
}

// ============ fallback kernels (used only if ws too small) ============
__global__ __launch_bounds__(256) void xx_kernel(const float* __restrict__ x,
                                                 float* __restrict__ xx) {
  int g = blockIdx.x * 256 + threadIdx.x;
  int b = g >> 11;
  int n = g & (N_ - 1);
  const float* xp = x + (size_t)b * C_ * N_ + n;
  float s = 0.f;
#pragma unroll 8
  for (int c = 0; c < C_; ++c) { float v = xp[(size_t)c * N_]; s += v * v; }
  xx[g] = s;
}

__global__ __launch_bounds__(256) void knn_kernel(const float* __restrict__ x,
                                                  const float* __restrict__ xx,
                                                  int* __restrict__ knn_out) {
  __shared__ __align__(16) float qT[C_ * 64];
  __shared__ __align__(16) float mT[C_ * 64];
  const int b = blockIdx.y;
  const int q0 = blockIdx.x * 64;
  const int t = threadIdx.x;
  const float* xb = x + (size_t)b * C_ * N_;
  const float* xxb = xx + b * N_;
  for (int i = t; i < C_ * 64; i += 256) {
    int c = i >> 6, q = i & 63;
    qT[i] = xb[(size_t)c * N_ + q0 + q];
  }
  const int tq = t & 15;
  const int tm = t >> 4;
  float bd[4][4]; int bi[4][4];
#pragma unroll
  for (int a = 0; a < 4; ++a)
#pragma unroll
    for (int s = 0; s < 4; ++s) { bd[a][s] = 1e30f; bi[a][s] = 0; }
  for (int m0 = 0; m0 < N_; m0 += 64) {
    __syncthreads();
    for (int i = t; i < C_ * 64; i += 256) {
      int c = i >> 6, m = i & 63;
      mT[i] = xb[(size_t)c * N_ + m0 + m];
    }
    __syncthreads();
    float acc[4][4];
#pragma unroll
    for (int a = 0; a < 4; ++a)
#pragma unroll
      for (int j = 0; j < 4; ++j) acc[a][j] = 0.f;
#pragma unroll 4
    for (int c = 0; c < C_; ++c) {
      float4 qv = *(const float4*)&qT[c * 64 + tq * 4];
      float4 mv = *(const float4*)&mT[c * 64 + tm * 4];
      float qa[4] = {qv.x, qv.y, qv.z, qv.w};
      float ma[4] = {mv.x, mv.y, mv.z, mv.w};
#pragma unroll
      for (int a = 0; a < 4; ++a)
#pragma unroll
        for (int j = 0; j < 4; ++j) acc[a][j] += qa[a] * ma[j];
    }
#pragma unroll
    for (int j = 0; j < 4; ++j) {
      float xm = xxb[m0 + tm * 4 + j];
      int id = m0 + tm * 4 + j;
#pragma unroll
      for (int a = 0; a < 4; ++a) {
        float d = xm - 2.f * acc[a][j];
        if (d < bd[a][3]) {
          bd[a][3] = d; bi[a][3] = id;
#pragma unroll
          for (int s = 3; s > 0; --s)
            if (bd[a][s] < bd[a][s - 1]) {
              float td = bd[a][s]; bd[a][s] = bd[a][s - 1]; bd[a][s - 1] = td;
              int ti = bi[a][s]; bi[a][s] = bi[a][s - 1]; bi[a][s - 1] = ti;
            }
        }
      }
    }
  }
  __syncthreads();
  float* cd = qT;
  int* ci = (int*)mT;
#pragma unroll
  for (int a = 0; a < 4; ++a) {
    int q = tq * 4 + a;
#pragma unroll
    for (int s = 0; s < 4; ++s) {
      cd[q * 64 + tm * 4 + s] = bd[a][s];
      ci[q * 64 + tm * 4 + s] = bi[a][s];
    }
  }
  __syncthreads();
  if (t < 64) {
    float fd[4]; int fi[4];
#pragma unroll
    for (int s = 0; s < 4; ++s) { fd[s] = 1e30f; fi[s] = 0; }
    for (int j = 0; j < 64; ++j) {
      float d = cd[t * 64 + j];
      int id = ci[t * 64 + j];
      if (d < fd[3]) {
        fd[3] = d; fi[3] = id;
#pragma unroll
        for (int s = 3; s > 0; --s)
          if (fd[s] < fd[s - 1]) {
            float td = fd[s]; fd[s] = fd[s - 1]; fd[s - 1] = td;
            int ti = fi[s]; fi[s] = fi[s - 1]; fi[s - 1] = ti;
          }
      }
    }
#pragma unroll
    for (int s = 0; s < 4; ++s)
      knn_out[(b * N_ + q0 + t) * K_ + s] = fi[s];
  }
}

// ============ fused: gather + e1 + e2 + e3 + max, bf16 MFMA ============
// LDS carve (bytes): cT 0..4352 | nT 4352..21760 | e1T 21760..30976 (oSt alias)
//                    e2T 30976..48384 | nidx 48384..48640
__global__ __launch_bounds__(256) void fused_mfma(
    const float* __restrict__ x, const u16* __restrict__ xh,
    const int* __restrict__ knn_idx,
    const float* __restrict__ w1, const float* __restrict__ b1,
    const float* __restrict__ w2, const float* __restrict__ b2,
    const float* __restrict__ w3, const float* __restrict__ b3,
    float* __restrict__ out) {
  __shared__ __align__(16) char fsm[48640];
  __bf16 (*cT)[136]  = (__bf16(*)[136])(fsm);
  __bf16 (*nT)[136]  = (__bf16(*)[136])(fsm + 4352);
  __bf16 (*e1T)[72]  = (__bf16(*)[72])(fsm + 21760);
  __bf16 (*e2T)[136] = (__bf16(*)[136])(fsm + 30976);
  float  (*oSt)[36]  = (float(*)[36])(fsm + 21760);
  int* nidx = (int*)(fsm + 48384);

  const int b  = blockIdx.y;
  const int n0 = blockIdx.x * 16;
  const int t  = threadIdx.x;
  const float* xb = x + (size_t)b * C_ * N_;
  const u16* xhb = xh ? xh + (size_t)b * N_ * C_ : nullptr;

  if (t < 64) nidx[t] = knn_idx[(b * N_ + n0 + (t >> 2)) * K_ + (t & 3)];
  __syncthreads();

  if (xhb) {
    // fast staging from bf16 rows (swizzle unapplied via chunk XOR)
    {
      int n = t >> 4, cb = t & 15;
      int gn = n0 + n;
      *(s16x8*)&cT[n][cb * 8] =
          *(const s16x8*)&xhb[(size_t)gn * C_ + ((cb ^ (gn & 7)) * 8)];
    }
#pragma unroll
    for (int it = 0; it < 4; ++it) {
      int u = t + it * 256;
      int col = u >> 4, cb = u & 15;
      int nid = nidx[col];
      *(s16x8*)&nT[col][cb * 8] =
          *(const s16x8*)&xhb[(size_t)nid * C_ + ((cb ^ (nid & 7)) * 8)];
    }
  } else {
    // fallback staging from fp32 x
    {
      int n = t >> 4, ch = t & 15;
      const float* src = xb + (size_t)(ch * 8) * N_ + n0 + n;
      bf16x8 raw;
#pragma unroll
      for (int j = 0; j < 8; ++j) raw[j] = (__bf16)src[(size_t)j * N_];
      *(bf16x8*)&cT[n][ch * 8] = raw;
    }
#pragma unroll
    for (int it = 0; it < 4; ++it) {
      int u = t + it * 256;
      int col = u >> 4, ch = u & 15;
      const float* src = xb + (size_t)(ch * 8) * N_ + nidx[col];
      bf16x8 raw;
#pragma unroll
      for (int j = 0; j < 8; ++j) raw[j] = (__bf16)src[(size_t)j * N_];
      *(bf16x8*)&nT[col][ch * 8] = raw;
    }
  }
  __syncthreads();

  const int lq = t & 15;
  const int lh = (t >> 4) & 3;
  const int wv = t >> 6;

  // ---- phase 1: e1 = relu(w1 @ f + b1), K=256 (raw f) ----
  {
    const float* w1r = w1 + (size_t)(wv * 16 + lq) * C2_;
    f32x4 acc[4];
#pragma unroll
    for (int cg = 0; cg < 4; ++cg) acc[cg] = (f32x4){0.f, 0.f, 0.f, 0.f};
#pragma unroll
    for (int ks = 0; ks < 8; ++ks) {
      s16x8 a = ldw_bf16(w1r + ks * 32 + lh * 8);
#pragma unroll
      for (int cg = 0; cg < 4; ++cg) {
        const __bf16* bp = (ks < 4)
            ? &cT[cg * 4 + (lq >> 2)][ks * 32 + lh * 8]
            : &nT[cg * 16 + lq][(ks - 4) * 32 + lh * 8];
        acc[cg] = __builtin_amdgcn_mfma_f32_16x16x32_bf16(
            a, *(const s16x8*)bp, acc[cg], 0, 0, 0);
      }
    }
#pragma unroll
    for (int cg = 0; cg < 4; ++cg) {
      bf16x4 st;
#pragma unroll
      for (int r = 0; r < 4; ++r) {
        float v = acc[cg][r] + b1[wv * 16 + lh * 4 + r];
        st[r] = (__bf16)fmaxf(v, 0.f);
      }
      *(bf16x4*)&e1T[cg * 16 + lq][wv * 16 + lh * 4] = st;
    }
  }
  __syncthreads();

  // ---- in-place relu of cT+nT (contiguous 21760 B = 5440 u32) ----
  {
    u32* fr = (u32*)fsm;
    for (int u = t; u < 5440; u += 256) fr[u] = relu2(fr[u]);
  }
  __syncthreads();

  // ---- phase 2: e2 = relu(w2 @ [relu(e1); relu(f)] + b2), K=320 ----
  {
    const float* w2r0 = w2 + (size_t)(wv * 32 + lq) * ED_;
    const float* w2r1 = w2r0 + (size_t)16 * ED_;
    f32x4 acc[2][4];
#pragma unroll
    for (int ro = 0; ro < 2; ++ro)
#pragma unroll
      for (int cg = 0; cg < 4; ++cg) acc[ro][cg] = (f32x4){0.f, 0.f, 0.f, 0.f};
#pragma unroll
    for (int ks = 0; ks < 10; ++ks) {
      s16x8 a0 = ldw_bf16(w2r0 + ks * 32 + lh * 8);
      s16x8 a1 = ldw_bf16(w2r1 + ks * 32 + lh * 8);
#pragma unroll
      for (int cg = 0; cg < 4; ++cg) {
        const __bf16* bp;
        if (ks < 2)      bp = &e1T[cg * 16 + lq][ks * 32 + lh * 8];
        else if (ks < 6) bp = &cT[cg * 4 + (lq >> 2)][(ks - 2) * 32 + lh * 8];
        else             bp = &nT[cg * 16 + lq][(ks - 6) * 32 + lh * 8];
        s16x8 bf = *(const s16x8*)bp;
        acc[0][cg] = __builtin_amdgcn_mfma_f32_16x16x32_bf16(a0, bf, acc[0][cg], 0, 0, 0);
        acc[1][cg] = __builtin_amdgcn_mfma_f32_16x16x32_bf16(a1, bf, acc[1][cg], 0, 0, 0);
      }
    }
#pragma unroll
    for (int ro = 0; ro < 2; ++ro)
#pragma unroll
      for (int cg = 0; cg < 4; ++cg) {
        bf16x4 st;
#pragma unroll
        for (int r = 0; r < 4; ++r) {
          float v = acc[ro][cg][r] + b2[wv * 32 + ro * 16 + lh * 4 + r];
          st[r] = (__bf16)fmaxf(v, 0.f);
        }
        *(bf16x4*)&e2T[cg * 16 + lq][wv * 32 + ro * 16 + lh * 4] = st;
      }
  }
  __syncthreads();

  // ---- phase 3: e3 = w3 @ e2' (K=64), max over k, +b3 ----
  {
    const float* w3r = w3 + (size_t)(wv * 16 + lq) * O_;
    s16x8 a0 = ldw_bf16(w3r + lh * 8);
    s16x8 a1 = ldw_bf16(w3r + 32 + lh * 8);
#pragma unroll
    for (int cg = 0; cg < 8; ++cg) {
      int col = cg * 16 + lq;
      int nl = col >> 3, rr = (col >> 2) & 1, kk = col & 3;
      const __bf16* base = &e2T[nl * 4 + kk][rr * 64];
      f32x4 acc = {0.f, 0.f, 0.f, 0.f};
      acc = __builtin_amdgcn_mfma_f32_16x16x32_bf16(a0, *(const s16x8*)(base + lh * 8),      acc, 0, 0, 0);
      acc = __builtin_amdgcn_mfma_f32_16x16x32_bf16(a1, *(const s16x8*)(base + 32 + lh * 8), acc, 0, 0, 0);
      float vv[4];
#pragma unroll
      for (int r = 0; r < 4; ++r) {
        float v = acc[r];
        v = fmaxf(v, __shfl_xor(v, 1));
        v = fmaxf(v, __shfl_xor(v, 2));
        vv[r] = v;
      }
      if ((lq & 3) == 0) {
        int mloc = col >> 2;
        int o = wv * 16 + lh * 4;
#pragma unroll
        for (int r = 0; r < 4; ++r) oSt[o + r][mloc] = vv[r] + b3[o + r];
      }
    }
  }
  __syncthreads();

#pragma unroll
  for (int it = 0; it < 2; ++it) {
    int u = t + it * 256;
    int o = u >> 3, seg = u & 7;
    *(float4*)&out[((size_t)b * O_ + o) * NM_ + n0 * 2 + seg * 4] =
        *(const float4*)&oSt[o][seg * 4];
  }
}

extern "C" void kernel_launch(void* const* d_in, const int* in_sizes, int n_in,
                              void* d_out, int out_size, void* d_ws, size_t ws_size,
                              hipStream_t stream) {
  const float* x  = (const float*)d_in[0];
  const float* w1 = (const float*)d_in[1];
  const float* b1 = (const float*)d_in[2];
  const float* w2 = (const float*)d_in[3];
  const float* b2 = (const float*)d_in[4];
  const float* w3 = (const float*)d_in[5];
  const float* b3 = (const float*)d_in[6];
  float* out = (float*)d_out;

  const size_t off_xT32 = 0;
  const size_t off_xh   = (size_t)B_ * N_ * C_ * 4;                 // 16 MB
  const size_t off_xx   = off_xh + (size_t)B_ * N_ * C_ * 2;        // +8 MB
  const size_t off_c8   = off_xx + (size_t)B_ * N_ * 4;             // +128 KB
  const size_t off_knn  = off_c8 + (size_t)B_ * N_ * 8 * 4;         // +1 MB
  const size_t NEED     = off_knn + (size_t)B_ * N_ * K_ * 4;       // +512 KB

  if (ws_size >= NEED) {
    float* xT32 = (float*)d_ws;
    u16*   xhp  = (u16*)((char*)d_ws + off_xh);
    float* xx   = (float*)((char*)d_ws + off_xx);
    int*   c8   = (int*)((char*)d_ws + off_c8);
    int*   knn  = (int*)((char*)d_ws + off_knn);

    hipLaunchKernelGGL(prep_kernel, dim3(N_ / 64, B_), dim3(256), 0, stream, x, xT32, xhp, xx);
    hipLaunchKernelGGL(knn_mfma, dim3(N_ / 64, B_), dim3(256), 0, stream, xhp, xx, c8);
    hipLaunchKernelGGL(rerank_kernel, dim3(N_ / 64, B_), dim3(256), 0, stream, xT32, xx, c8, knn);
    hipLaunchKernelGGL(fused_mfma, dim3(N_ / 16, B_), dim3(256), 0, stream,
                       x, xhp, knn, w1, b1, w2, b2, w3, b3, out);
  } else {
    float* xx = (float*)d_ws;
    int* knn = (int*)((char*)d_ws + (size_t)B_ * N_ * 4);
    hipLaunchKernelGGL(xx_kernel, dim3((B_ * N_) / 256), dim3(256), 0, stream, x, xx);
    hipLaunchKernelGGL(knn_kernel, dim3(N_ / 64, B_), dim3(256), 0, stream, x, xx, knn);
    hipLaunchKernelGGL(fused_mfma, dim3(N_ / 16, B_), dim3(256), 0, stream,
                       x, (const u16*)nullptr, knn, w1, b1, w2, b2, w3, b3, out);
  }
}

// Round 4
// 126.967 us; speedup vs baseline: 5.3164x; 1.6141x over previous
//
#include <hip/hip_runtime.h>
#include <cstdint>
#include <cstddef>

#define B_  16
#define C_  128
#define N_  2048
#define K_  4
#define O_  64
#define C2_ 256   // 2*C
#define ED_ 320   // 2*C + O
#define NM_ 4096  // N*R

typedef float  f32x4  __attribute__((ext_vector_type(4)));
typedef short  s16x8  __attribute__((ext_vector_type(8)));
typedef __bf16 bf16x4 __attribute__((ext_vector_type(4)));
typedef __bf16 bf16x8 __attribute__((ext_vector_type(8)));
typedef unsigned short u16;
typedef unsigned int   u32;

__device__ __forceinline__ u32 umin32(u32 a, u32 b) { return a < b ? a : b; }
__device__ __forceinline__ u32 umax32(u32 a, u32 b) { return a > b ? a : b; }

__device__ __forceinline__ s16x8 ldw_bf16(const float* __restrict__ p) {
  float4 a = *(const float4*)p;
  float4 c = *(const float4*)(p + 4);
  bf16x8 r;
  r[0] = (__bf16)a.x; r[1] = (__bf16)a.y; r[2] = (__bf16)a.z; r[3] = (__bf16)a.w;
  r[4] = (__bf16)c.x; r[5] = (__bf16)c.y; r[6] = (__bf16)c.z; r[7] = (__bf16)c.w;
  return __builtin_bit_cast(s16x8, r);
}

// relu on 2 packed bf16 in a u32: sign-bit -> zero the half
__device__ __forceinline__ u32 relu2(u32 u) {
  u32 s = u & 0x80008000u;
  u32 m = s - (s >> 15);
  return u & ~(m | s);
}

__device__ __forceinline__ void glds16(const void* g, void* l) {
  __builtin_amdgcn_global_load_lds(
      (const __attribute__((address_space(1))) u32*)g,
      (__attribute__((address_space(3))) u32*)l, 16, 0, 0);
}

// ============ prep: xx, xT32 (fp32 rows), xh (bf16 rows, XOR-swizzled),
//              and (blockIdx.y==B_) weight f32->bf16 conversion ============
__global__ __launch_bounds__(256) void prep_kernel(const float* __restrict__ x,
                                                   const float* __restrict__ w1,
                                                   const float* __restrict__ w2,
                                                   const float* __restrict__ w3,
                                                   float* __restrict__ xT32,
                                                   u16* __restrict__ xh,
                                                   float* __restrict__ xx,
                                                   u16* __restrict__ wh) {
  const int t = threadIdx.x;
  if (blockIdx.y == B_) {
    // weights: w1 4096 quads | w2 10240 quads | w3 1024 quads = 15360
    const int gid = blockIdx.x * 256 + t;   // 0..8191
    for (int i = gid; i < 15360; i += 8192) {
      const float* src; u16* dst;
      if (i < 4096)       { src = w1 + (size_t)i * 4;            dst = wh + (size_t)i * 4; }
      else if (i < 14336) { src = w2 + (size_t)(i - 4096) * 4;   dst = wh + 16384 + (size_t)(i - 4096) * 4; }
      else                { src = w3 + (size_t)(i - 14336) * 4;  dst = wh + 57344 + (size_t)(i - 14336) * 4; }
      float4 v = *(const float4*)src;
      ushort4 h;
      h.x = __builtin_bit_cast(u16, (__bf16)v.x);
      h.y = __builtin_bit_cast(u16, (__bf16)v.y);
      h.z = __builtin_bit_cast(u16, (__bf16)v.z);
      h.w = __builtin_bit_cast(u16, (__bf16)v.w);
      *(ushort4*)dst = h;
    }
    return;
  }

  __shared__ __align__(16) float sx[C_][65];
  const int b = blockIdx.y, n0 = blockIdx.x * 64;
  const float* xb = x + (size_t)b * C_ * N_;
  for (int u = t; u < C_ * 16; u += 256) {
    int c = u >> 4, f4 = u & 15;
    float4 v = *(const float4*)&xb[(size_t)c * N_ + n0 + f4 * 4];
    sx[c][f4 * 4 + 0] = v.x; sx[c][f4 * 4 + 1] = v.y;
    sx[c][f4 * 4 + 2] = v.z; sx[c][f4 * 4 + 3] = v.w;
  }
  __syncthreads();
  if (t < 64) {
    float s = 0.f;
    for (int c = 0; c < C_; ++c) { float v = sx[c][t]; s = fmaf(v, v, s); }
    xx[b * N_ + n0 + t] = s;
  }
  for (int u = t; u < 64 * 16; u += 256) {
    int n = u >> 4, cb = u & 15;
    float vv[8]; s16x8 hv;
#pragma unroll
    for (int j = 0; j < 8; ++j) {
      float v = sx[cb * 8 + j][n];
      vv[j] = v;
      hv[j] = (short)__builtin_bit_cast(u16, (__bf16)v);
    }
    size_t ro = ((size_t)b * N_ + n0 + n) * C_;
    *(float4*)&xT32[ro + cb * 8]     = make_float4(vv[0], vv[1], vv[2], vv[3]);
    *(float4*)&xT32[ro + cb * 8 + 4] = make_float4(vv[4], vv[5], vv[6], vv[7]);
    int sc = cb ^ (n & 7);
    *(s16x8*)&xh[ro + sc * 8] = hv;
  }
}

// ============ knn stage 1: bf16 hh MFMA distances -> top-8 candidates/query
//              (branchless packed u32 top-5 per unit) ============
__global__ __launch_bounds__(256) void knn_mfma(const u16* __restrict__ xh,
                                                const float* __restrict__ xx,
                                                int* __restrict__ cand8) {
  __shared__ __align__(16) char smem[40960];  // 2x16KB staging; merge aliases 64x85 u32
  const int b = blockIdx.y, q0 = blockIdx.x * 64;
  const int t = threadIdx.x;
  const int lane = t & 63, wv = t >> 6, lq = t & 15, lh = (t >> 4) & 3;
  const u16* xhb = xh + (size_t)b * N_ * C_;
  const float* xxb = xx + b * N_;

  // Q fragments (B-operand), held in registers for the whole kernel
  s16x8 qf[4][4];
#pragma unroll
  for (int qt = 0; qt < 4; ++qt)
#pragma unroll
    for (int ks = 0; ks < 4; ++ks) {
      int q = q0 + qt * 16 + lq;
      int ch = (ks * 4 + lh) ^ (q & 7);
      qf[qt][ks] = *(const s16x8*)&xhb[(size_t)q * C_ + ch * 8];
    }

  // packed top-5 per (lane, qt): (orderable-dist & ~0x7FF) | m_idx, ascending
  u32 pk[4][5];
#pragma unroll
  for (int qt = 0; qt < 4; ++qt)
#pragma unroll
    for (int s = 0; s < 5; ++s) pk[qt][s] = 0xFFFFFFFFu;

  auto stage = [&](int bufi, int m0) {
    const char* s = (const char*)(xhb + (size_t)m0 * C_);
    char* d = smem + bufi * 16384;
#pragma unroll
    for (int c = 0; c < 4; ++c) {
      int off = (wv * 4 + c) * 1024;
      glds16(s + off + lane * 16, d + off);
    }
  };

  stage(0, 0);
  asm volatile("s_waitcnt vmcnt(0)");
  __syncthreads();

  for (int step = 0; step < 32; ++step) {
    const int cur = step & 1;
    if (step < 31) stage(cur ^ 1, (step + 1) * 64);
    const char* mb = smem + cur * 16384;
    f32x4 acc[4];
#pragma unroll
    for (int qt = 0; qt < 4; ++qt) acc[qt] = (f32x4){0.f, 0.f, 0.f, 0.f};
#pragma unroll
    for (int ks = 0; ks < 4; ++ks) {
      int row = wv * 16 + lq;
      int ch = (ks * 4 + lh) ^ (lq & 7);
      s16x8 mf = *(const s16x8*)(mb + row * 256 + ch * 16);
#pragma unroll
      for (int qt = 0; qt < 4; ++qt)
        acc[qt] = __builtin_amdgcn_mfma_f32_16x16x32_bf16(mf, qf[qt][ks], acc[qt], 0, 0, 0);
    }
    const int mrow = step * 64 + wv * 16 + lh * 4;
    float4 xm4 = *(const float4*)&xxb[mrow];
    float xma[4] = {xm4.x, xm4.y, xm4.z, xm4.w};
#pragma unroll
    for (int r = 0; r < 4; ++r) {
#pragma unroll
      for (int qt = 0; qt < 4; ++qt) {   // 4 independent chains -> ILP
        float dd = fmaf(acc[qt][r], -2.f, xma[r]);
        u32 s = __builtin_bit_cast(u32, dd);
        u32 neg = (u32)((int)s >> 31);
        u32 u = s ^ (neg | 0x80000000u);
        u32 v = (u & 0xFFFFF800u) | (u32)(mrow + r);
#pragma unroll
        for (int s5 = 0; s5 < 5; ++s5) {
          u32 lo = umin32(v, pk[qt][s5]);
          v = umax32(v, pk[qt][s5]);
          pk[qt][s5] = lo;
        }
      }
    }
    asm volatile("s_waitcnt vmcnt(0)");
    __syncthreads();
  }

  // merge: per local q, 16 units x 5 packed candidates (row stride 85 -> no bank camping)
  u32* cd = (u32*)smem;
  const int unit = wv * 4 + lh;
#pragma unroll
  for (int qt = 0; qt < 4; ++qt) {
    int ql = qt * 16 + lq;
#pragma unroll
    for (int s = 0; s < 5; ++s) cd[ql * 85 + unit * 5 + s] = pk[qt][s];
  }
  __syncthreads();
  if (t < 64) {
    u32 fd[8];
#pragma unroll
    for (int s = 0; s < 8; ++s) fd[s] = 0xFFFFFFFFu;
    for (int j = 0; j < 80; ++j) {
      u32 v = cd[t * 85 + j];
#pragma unroll
      for (int s = 0; s < 8; ++s) {
        u32 lo = umin32(v, fd[s]);
        v = umax32(v, fd[s]);
        fd[s] = lo;
      }
    }
#pragma unroll
    for (int s = 0; s < 8; ++s)
      cand8[((size_t)b * N_ + q0 + t) * 8 + s] = (int)(fd[s] & 0x7FFu);
  }
}

// ============ knn stage 2: exact fp32 rerank of 8 candidates -> top-4 ============
__global__ __launch_bounds__(256) void rerank_kernel(const float* __restrict__ xT32,
                                                     const float* __restrict__ xx,
                                                     const int* __restrict__ cand8,
                                                     int* __restrict__ knn_out) {
  __shared__ __align__(16) float sq[64][132];
  __shared__ float sd[64][8];
  __shared__ int   si[64][8];
  const int b = blockIdx.y, n0 = blockIdx.x * 64;
  const int t = threadIdx.x;
  const float* xb32 = xT32 + (size_t)b * N_ * C_;
  for (int u = t; u < 64 * 32; u += 256) {
    int n = u >> 5, seg = u & 31;
    *(float4*)&sq[n][seg * 4] = *(const float4*)&xb32[(size_t)(n0 + n) * C_ + seg * 4];
  }
  __syncthreads();
  const int ql = t >> 2, cs = t & 3;
#pragma unroll
  for (int cc = 0; cc < 2; ++cc) {
    int cslot = cs + cc * 4;
    int idx = cand8[((size_t)b * N_ + n0 + ql) * 8 + cslot];
    const float* mr = &xb32[(size_t)idx * C_];
    float a0 = 0.f, a1 = 0.f, a2 = 0.f, a3 = 0.f;
#pragma unroll 8
    for (int i = 0; i < 32; ++i) {
      float4 qv = *(const float4*)&sq[ql][i * 4];
      float4 mv = *(const float4*)&mr[i * 4];
      a0 = fmaf(qv.x, mv.x, a0); a1 = fmaf(qv.y, mv.y, a1);
      a2 = fmaf(qv.z, mv.z, a2); a3 = fmaf(qv.w, mv.w, a3);
    }
    float dot = (a0 + a1) + (a2 + a3);
    sd[ql][cslot] = xx[(size_t)b * N_ + idx] - 2.f * dot;
    si[ql][cslot] = idx;
  }
  __syncthreads();
  if (t < 64) {
    float dloc[8]; int iloc[8];
#pragma unroll
    for (int j = 0; j < 8; ++j) { dloc[j] = sd[t][j]; iloc[j] = si[t][j]; }
    u32 used = 0;
#pragma unroll
    for (int s = 0; s < 4; ++s) {
      float bdv = 1e30f; int bidx = 0x7fffffff; int bj = 0;
#pragma unroll
      for (int j = 0; j < 8; ++j) {
        if (!((used >> j) & 1)) {
          bool bet = (dloc[j] < bdv) || (dloc[j] == bdv && iloc[j] < bidx);
          if (bet) { bdv = dloc[j]; bidx = iloc[j]; bj = j; }
        }
      }
      used |= 1u << bj;
      knn_out[((size_t)b * N_ + n0 + t) * K_ + s] = bidx;
    }
  }
}

// ============ fallback kernels (used only if ws too small) ============
__global__ __launch_bounds__(256) void xx_kernel(const float* __restrict__ x,
                                                 float* __restrict__ xx) {
  int g = blockIdx.x * 256 + threadIdx.x;
  int b = g >> 11;
  int n = g & (N_ - 1);
  const float* xp = x + (size_t)b * C_ * N_ + n;
  float s = 0.f;
#pragma unroll 8
  for (int c = 0; c < C_; ++c) { float v = xp[(size_t)c * N_]; s += v * v; }
  xx[g] = s;
}

__global__ __launch_bounds__(256) void knn_kernel(const float* __restrict__ x,
                                                  const float* __restrict__ xx,
                                                  int* __restrict__ knn_out) {
  __shared__ __align__(16) float qT[C_ * 64];
  __shared__ __align__(16) float mT[C_ * 64];
  const int b = blockIdx.y;
  const int q0 = blockIdx.x * 64;
  const int t = threadIdx.x;
  const float* xb = x + (size_t)b * C_ * N_;
  const float* xxb = xx + b * N_;
  for (int i = t; i < C_ * 64; i += 256) {
    int c = i >> 6, q = i & 63;
    qT[i] = xb[(size_t)c * N_ + q0 + q];
  }
  const int tq = t & 15;
  const int tm = t >> 4;
  float bd[4][4]; int bi[4][4];
#pragma unroll
  for (int a = 0; a < 4; ++a)
#pragma unroll
    for (int s = 0; s < 4; ++s) { bd[a][s] = 1e30f; bi[a][s] = 0; }
  for (int m0 = 0; m0 < N_; m0 += 64) {
    __syncthreads();
    for (int i = t; i < C_ * 64; i += 256) {
      int c = i >> 6, m = i & 63;
      mT[i] = xb[(size_t)c * N_ + m0 + m];
    }
    __syncthreads();
    float acc[4][4];
#pragma unroll
    for (int a = 0; a < 4; ++a)
#pragma unroll
      for (int j = 0; j < 4; ++j) acc[a][j] = 0.f;
#pragma unroll 4
    for (int c = 0; c < C_; ++c) {
      float4 qv = *(const float4*)&qT[c * 64 + tq * 4];
      float4 mv = *(const float4*)&mT[c * 64 + tm * 4];
      float qa[4] = {qv.x, qv.y, qv.z, qv.w};
      float ma[4] = {mv.x, mv.y, mv.z, mv.w};
#pragma unroll
      for (int a = 0; a < 4; ++a)
#pragma unroll
        for (int j = 0; j < 4; ++j) acc[a][j] += qa[a] * ma[j];
    }
#pragma unroll
    for (int j = 0; j < 4; ++j) {
      float xm = xxb[m0 + tm * 4 + j];
      int id = m0 + tm * 4 + j;
#pragma unroll
      for (int a = 0; a < 4; ++a) {
        float d = xm - 2.f * acc[a][j];
        if (d < bd[a][3]) {
          bd[a][3] = d; bi[a][3] = id;
#pragma unroll
          for (int s = 3; s > 0; --s)
            if (bd[a][s] < bd[a][s - 1]) {
              float td = bd[a][s]; bd[a][s] = bd[a][s - 1]; bd[a][s - 1] = td;
              int ti = bi[a][s]; bi[a][s] = bi[a][s - 1]; bi[a][s - 1] = ti;
            }
        }
      }
    }
  }
  __syncthreads();
  float* cd = qT;
  int* ci = (int*)mT;
#pragma unroll
  for (int a = 0; a < 4; ++a) {
    int q = tq * 4 + a;
#pragma unroll
    for (int s = 0; s < 4; ++s) {
      cd[q * 64 + tm * 4 + s] = bd[a][s];
      ci[q * 64 + tm * 4 + s] = bi[a][s];
    }
  }
  __syncthreads();
  if (t < 64) {
    float fd[4]; int fi[4];
#pragma unroll
    for (int s = 0; s < 4; ++s) { fd[s] = 1e30f; fi[s] = 0; }
    for (int j = 0; j < 64; ++j) {
      float d = cd[t * 64 + j];
      int id = ci[t * 64 + j];
      if (d < fd[3]) {
        fd[3] = d; fi[3] = id;
#pragma unroll
        for (int s = 3; s > 0; --s)
          if (fd[s] < fd[s - 1]) {
            float td = fd[s]; fd[s] = fd[s - 1]; fd[s - 1] = td;
            int ti = fi[s]; fi[s] = fi[s - 1]; fi[s - 1] = ti;
          }
      }
    }
#pragma unroll
    for (int s = 0; s < 4; ++s)
      knn_out[(b * N_ + q0 + t) * K_ + s] = fi[s];
  }
}

// ============ fused: gather + e1 + e2 + e3 + max, bf16 MFMA ============
// LDS carve (bytes): cT 0..4352 | nT 4352..21760 | e1T 21760..30976 (oSt alias)
//                    e2T 30976..48384 | nidx 48384..48640
__global__ __launch_bounds__(256) void fused_mfma(
    const float* __restrict__ x, const u16* __restrict__ xh,
    const u16* __restrict__ wh, const int* __restrict__ knn_idx,
    const float* __restrict__ w1, const float* __restrict__ b1,
    const float* __restrict__ w2, const float* __restrict__ b2,
    const float* __restrict__ w3, const float* __restrict__ b3,
    float* __restrict__ out) {
  __shared__ __align__(16) char fsm[48640];
  __bf16 (*cT)[136]  = (__bf16(*)[136])(fsm);
  __bf16 (*nT)[136]  = (__bf16(*)[136])(fsm + 4352);
  __bf16 (*e1T)[72]  = (__bf16(*)[72])(fsm + 21760);
  __bf16 (*e2T)[136] = (__bf16(*)[136])(fsm + 30976);
  float  (*oSt)[36]  = (float(*)[36])(fsm + 21760);
  int* nidx = (int*)(fsm + 48384);

  const int b  = blockIdx.y;
  const int n0 = blockIdx.x * 16;
  const int t  = threadIdx.x;
  const float* xb = x + (size_t)b * C_ * N_;
  const u16* xhb = xh ? xh + (size_t)b * N_ * C_ : nullptr;
  const u16* w1h = wh;            // [64][256]
  const u16* w2h = wh + 16384;    // [128][320]
  const u16* w3h = wh + 57344;    // [64][64]

  if (t < 64) nidx[t] = knn_idx[(b * N_ + n0 + (t >> 2)) * K_ + (t & 3)];
  __syncthreads();

  if (xhb) {
    {
      int n = t >> 4, cb = t & 15;
      int gn = n0 + n;
      *(s16x8*)&cT[n][cb * 8] =
          *(const s16x8*)&xhb[(size_t)gn * C_ + ((cb ^ (gn & 7)) * 8)];
    }
#pragma unroll
    for (int it = 0; it < 4; ++it) {
      int u = t + it * 256;
      int col = u >> 4, cb = u & 15;
      int nid = nidx[col];
      *(s16x8*)&nT[col][cb * 8] =
          *(const s16x8*)&xhb[(size_t)nid * C_ + ((cb ^ (nid & 7)) * 8)];
    }
  } else {
    {
      int n = t >> 4, ch = t & 15;
      const float* src = xb + (size_t)(ch * 8) * N_ + n0 + n;
      bf16x8 raw;
#pragma unroll
      for (int j = 0; j < 8; ++j) raw[j] = (__bf16)src[(size_t)j * N_];
      *(bf16x8*)&cT[n][ch * 8] = raw;
    }
#pragma unroll
    for (int it = 0; it < 4; ++it) {
      int u = t + it * 256;
      int col = u >> 4, ch = u & 15;
      const float* src = xb + (size_t)(ch * 8) * N_ + nidx[col];
      bf16x8 raw;
#pragma unroll
      for (int j = 0; j < 8; ++j) raw[j] = (__bf16)src[(size_t)j * N_];
      *(bf16x8*)&nT[col][ch * 8] = raw;
    }
  }
  __syncthreads();

  const int lq = t & 15;
  const int lh = (t >> 4) & 3;
  const int wv = t >> 6;

  // ---- phase 1: e1 = relu(w1 @ f + b1), K=256 (raw f) ----
  {
    const u16* w1hr = w1h + (size_t)(wv * 16 + lq) * C2_;
    const float* w1r = w1 + (size_t)(wv * 16 + lq) * C2_;
    f32x4 acc[4];
#pragma unroll
    for (int cg = 0; cg < 4; ++cg) acc[cg] = (f32x4){0.f, 0.f, 0.f, 0.f};
#pragma unroll
    for (int ks = 0; ks < 8; ++ks) {
      s16x8 a = wh ? *(const s16x8*)&w1hr[ks * 32 + lh * 8]
                   : ldw_bf16(w1r + ks * 32 + lh * 8);
#pragma unroll
      for (int cg = 0; cg < 4; ++cg) {
        const __bf16* bp = (ks < 4)
            ? &cT[cg * 4 + (lq >> 2)][ks * 32 + lh * 8]
            : &nT[cg * 16 + lq][(ks - 4) * 32 + lh * 8];
        acc[cg] = __builtin_amdgcn_mfma_f32_16x16x32_bf16(
            a, *(const s16x8*)bp, acc[cg], 0, 0, 0);
      }
    }
#pragma unroll
    for (int cg = 0; cg < 4; ++cg) {
      bf16x4 st;
#pragma unroll
      for (int r = 0; r < 4; ++r) {
        float v = acc[cg][r] + b1[wv * 16 + lh * 4 + r];
        st[r] = (__bf16)fmaxf(v, 0.f);
      }
      *(bf16x4*)&e1T[cg * 16 + lq][wv * 16 + lh * 4] = st;
    }
  }
  __syncthreads();

  // ---- in-place relu of cT+nT (contiguous 21760 B = 5440 u32) ----
  {
    u32* fr = (u32*)fsm;
    for (int u = t; u < 5440; u += 256) fr[u] = relu2(fr[u]);
  }
  __syncthreads();

  // ---- phase 2: e2 = relu(w2 @ [relu(e1); relu(f)] + b2), K=320 ----
  {
    const u16* w2hr0 = w2h + (size_t)(wv * 32 + lq) * ED_;
    const u16* w2hr1 = w2hr0 + (size_t)16 * ED_;
    const float* w2r0 = w2 + (size_t)(wv * 32 + lq) * ED_;
    const float* w2r1 = w2r0 + (size_t)16 * ED_;
    f32x4 acc[2][4];
#pragma unroll
    for (int ro = 0; ro < 2; ++ro)
#pragma unroll
      for (int cg = 0; cg < 4; ++cg) acc[ro][cg] = (f32x4){0.f, 0.f, 0.f, 0.f};
#pragma unroll
    for (int ks = 0; ks < 10; ++ks) {
      s16x8 a0 = wh ? *(const s16x8*)&w2hr0[ks * 32 + lh * 8]
                    : ldw_bf16(w2r0 + ks * 32 + lh * 8);
      s16x8 a1 = wh ? *(const s16x8*)&w2hr1[ks * 32 + lh * 8]
                    : ldw_bf16(w2r1 + ks * 32 + lh * 8);
#pragma unroll
      for (int cg = 0; cg < 4; ++cg) {
        const __bf16* bp;
        if (ks < 2)      bp = &e1T[cg * 16 + lq][ks * 32 + lh * 8];
        else if (ks < 6) bp = &cT[cg * 4 + (lq >> 2)][(ks - 2) * 32 + lh * 8];
        else             bp = &nT[cg * 16 + lq][(ks - 6) * 32 + lh * 8];
        s16x8 bf = *(const s16x8*)bp;
        acc[0][cg] = __builtin_amdgcn_mfma_f32_16x16x32_bf16(a0, bf, acc[0][cg], 0, 0, 0);
        acc[1][cg] = __builtin_amdgcn_mfma_f32_16x16x32_bf16(a1, bf, acc[1][cg], 0, 0, 0);
      }
    }
#pragma unroll
    for (int ro = 0; ro < 2; ++ro)
#pragma unroll
      for (int cg = 0; cg < 4; ++cg) {
        bf16x4 st;
#pragma unroll
        for (int r = 0; r < 4; ++r) {
          float v = acc[ro][cg][r] + b2[wv * 32 + ro * 16 + lh * 4 + r];
          st[r] = (__bf16)fmaxf(v, 0.f);
        }
        *(bf16x4*)&e2T[cg * 16 + lq][wv * 32 + ro * 16 + lh * 4] = st;
      }
  }
  __syncthreads();

  // ---- phase 3: e3 = w3 @ e2' (K=64), max over k, +b3 ----
  {
    s16x8 a0, a1;
    if (wh) {
      const u16* w3hr = w3h + (size_t)(wv * 16 + lq) * O_;
      a0 = *(const s16x8*)&w3hr[lh * 8];
      a1 = *(const s16x8*)&w3hr[32 + lh * 8];
    } else {
      const float* w3r = w3 + (size_t)(wv * 16 + lq) * O_;
      a0 = ldw_bf16(w3r + lh * 8);
      a1 = ldw_bf16(w3r + 32 + lh * 8);
    }
#pragma unroll
    for (int cg = 0; cg < 8; ++cg) {
      int col = cg * 16 + lq;
      int nl = col >> 3, rr = (col >> 2) & 1, kk = col & 3;
      const __bf16* base = &e2T[nl * 4 + kk][rr * 64];
      f32x4 acc = {0.f, 0.f, 0.f, 0.f};
      acc = __builtin_amdgcn_mfma_f32_16x16x32_bf16(a0, *(const s16x8*)(base + lh * 8),      acc, 0, 0, 0);
      acc = __builtin_amdgcn_mfma_f32_16x16x32_bf16(a1, *(const s16x8*)(base + 32 + lh * 8), acc, 0, 0, 0);
      float vv[4];
#pragma unroll
      for (int r = 0; r < 4; ++r) {
        float v = acc[r];
        v = fmaxf(v, __shfl_xor(v, 1));
        v = fmaxf(v, __shfl_xor(v, 2));
        vv[r] = v;
      }
      if ((lq & 3) == 0) {
        int mloc = col >> 2;
        int o = wv * 16 + lh * 4;
#pragma unroll
        for (int r = 0; r < 4; ++r) oSt[o + r][mloc] = vv[r] + b3[o + r];
      }
    }
  }
  __syncthreads();

#pragma unroll
  for (int it = 0; it < 2; ++it) {
    int u = t + it * 256;
    int o = u >> 3, seg = u & 7;
    *(float4*)&out[((size_t)b * O_ + o) * NM_ + n0 * 2 + seg * 4] =
        *(const float4*)&oSt[o][seg * 4];
  }
}

extern "C" void kernel_launch(void* const* d_in, const int* in_sizes, int n_in,
                              void* d_out, int out_size, void* d_ws, size_t ws_size,
                              hipStream_t stream) {
  const float* x  = (const float*)d_in[0];
  const float* w1 = (const float*)d_in[1];
  const float* b1 = (const float*)d_in[2];
  const float* w2 = (const float*)d_in[3];
  const float* b2 = (const float*)d_in[4];
  const float* w3 = (const float*)d_in[5];
  const float* b3 = (const float*)d_in[6];
  float* out = (float*)d_out;

  const size_t off_xh   = (size_t)B_ * N_ * C_ * 4;                 // 16 MB
  const size_t off_xx   = off_xh + (size_t)B_ * N_ * C_ * 2;        // +8 MB
  const size_t off_c8   = off_xx + (size_t)B_ * N_ * 4;             // +128 KB
  const size_t off_knn  = off_c8 + (size_t)B_ * N_ * 8 * 4;         // +1 MB
  const size_t off_wh   = off_knn + (size_t)B_ * N_ * K_ * 4;       // +512 KB
  const size_t NEED     = off_wh + (size_t)61440 * 2;               // +120 KB

  if (ws_size >= NEED) {
    float* xT32 = (float*)d_ws;
    u16*   xhp  = (u16*)((char*)d_ws + off_xh);
    float* xx   = (float*)((char*)d_ws + off_xx);
    int*   c8   = (int*)((char*)d_ws + off_c8);
    int*   knn  = (int*)((char*)d_ws + off_knn);
    u16*   whp  = (u16*)((char*)d_ws + off_wh);

    hipLaunchKernelGGL(prep_kernel, dim3(N_ / 64, B_ + 1), dim3(256), 0, stream,
                       x, w1, w2, w3, xT32, xhp, xx, whp);
    hipLaunchKernelGGL(knn_mfma, dim3(N_ / 64, B_), dim3(256), 0, stream, xhp, xx, c8);
    hipLaunchKernelGGL(rerank_kernel, dim3(N_ / 64, B_), dim3(256), 0, stream, xT32, xx, c8, knn);
    hipLaunchKernelGGL(fused_mfma, dim3(N_ / 16, B_), dim3(256), 0, stream,
                       x, xhp, whp, knn, w1, b1, w2, b2, w3, b3, out);
  } else {
    float* xx = (float*)d_ws;
    int* knn = (int*)((char*)d_ws + (size_t)B_ * N_ * 4);
    hipLaunchKernelGGL(xx_kernel, dim3((B_ * N_) / 256), dim3(256), 0, stream, x, xx);
    hipLaunchKernelGGL(knn_kernel, dim3(N_ / 64, B_), dim3(256), 0, stream, x, xx, knn);
    hipLaunchKernelGGL(fused_mfma, dim3(N_ / 16, B_), dim3(256), 0, stream,
                       x, (const u16*)nullptr, (const u16*)nullptr, knn,
                       w1, b1, w2, b2, w3, b3, out);
  }
}

// Round 5
// 119.097 us; speedup vs baseline: 5.6677x; 1.0661x over previous
//
#include <hip/hip_runtime.h>
#include <cstdint>
#include <cstddef>

#define B_  16
#define C_  128
#define N_  2048
#define K_  4
#define O_  64
#define C2_ 256   // 2*C
#define ED_ 320   // 2*C + O
#define NM_ 4096  // N*R

typedef float  f32x4  __attribute__((ext_vector_type(4)));
typedef short  s16x8  __attribute__((ext_vector_type(8)));
typedef __bf16 bf16x4 __attribute__((ext_vector_type(4)));
typedef __bf16 bf16x8 __attribute__((ext_vector_type(8)));
typedef unsigned short u16;
typedef unsigned int   u32;
typedef unsigned int   u32x4 __attribute__((ext_vector_type(4)));

__device__ __forceinline__ u32 umin32(u32 a, u32 b) { return a < b ? a : b; }
__device__ __forceinline__ u32 umax32(u32 a, u32 b) { return a > b ? a : b; }

__device__ __forceinline__ s16x8 ldw_bf16(const float* __restrict__ p) {
  float4 a = *(const float4*)p;
  float4 c = *(const float4*)(p + 4);
  bf16x8 r;
  r[0] = (__bf16)a.x; r[1] = (__bf16)a.y; r[2] = (__bf16)a.z; r[3] = (__bf16)a.w;
  r[4] = (__bf16)c.x; r[5] = (__bf16)c.y; r[6] = (__bf16)c.z; r[7] = (__bf16)c.w;
  return __builtin_bit_cast(s16x8, r);
}

// relu on 2 packed bf16 in a u32: sign-bit -> zero the half
__device__ __forceinline__ u32 relu2(u32 u) {
  u32 s = u & 0x80008000u;
  u32 m = s - (s >> 15);
  return u & ~(m | s);
}

// relu on a whole bf16x8 fragment in registers
__device__ __forceinline__ s16x8 relu8(s16x8 v) {
  u32x4 u = __builtin_bit_cast(u32x4, v);
  u[0] = relu2(u[0]); u[1] = relu2(u[1]);
  u[2] = relu2(u[2]); u[3] = relu2(u[3]);
  return __builtin_bit_cast(s16x8, u);
}

__device__ __forceinline__ void glds16(const void* g, void* l) {
  __builtin_amdgcn_global_load_lds(
      (const __attribute__((address_space(1))) u32*)g,
      (__attribute__((address_space(3))) u32*)l, 16, 0, 0);
}

// ============ prep: xx, xT32 (fp32 rows), xh (bf16 rows, XOR-swizzled),
//              and (blockIdx.y==B_) weight f32->bf16 conversion ============
__global__ __launch_bounds__(256) void prep_kernel(const float* __restrict__ x,
                                                   const float* __restrict__ w1,
                                                   const float* __restrict__ w2,
                                                   const float* __restrict__ w3,
                                                   float* __restrict__ xT32,
                                                   u16* __restrict__ xh,
                                                   float* __restrict__ xx,
                                                   u16* __restrict__ wh) {
  const int t = threadIdx.x;
  if (blockIdx.y == B_) {
    const int gid = blockIdx.x * 256 + t;   // 0..8191
    for (int i = gid; i < 15360; i += 8192) {
      const float* src; u16* dst;
      if (i < 4096)       { src = w1 + (size_t)i * 4;            dst = wh + (size_t)i * 4; }
      else if (i < 14336) { src = w2 + (size_t)(i - 4096) * 4;   dst = wh + 16384 + (size_t)(i - 4096) * 4; }
      else                { src = w3 + (size_t)(i - 14336) * 4;  dst = wh + 57344 + (size_t)(i - 14336) * 4; }
      float4 v = *(const float4*)src;
      ushort4 h;
      h.x = __builtin_bit_cast(u16, (__bf16)v.x);
      h.y = __builtin_bit_cast(u16, (__bf16)v.y);
      h.z = __builtin_bit_cast(u16, (__bf16)v.z);
      h.w = __builtin_bit_cast(u16, (__bf16)v.w);
      *(ushort4*)dst = h;
    }
    return;
  }

  __shared__ __align__(16) float sx[C_][65];
  const int b = blockIdx.y, n0 = blockIdx.x * 64;
  const float* xb = x + (size_t)b * C_ * N_;
  for (int u = t; u < C_ * 16; u += 256) {
    int c = u >> 4, f4 = u & 15;
    float4 v = *(const float4*)&xb[(size_t)c * N_ + n0 + f4 * 4];
    sx[c][f4 * 4 + 0] = v.x; sx[c][f4 * 4 + 1] = v.y;
    sx[c][f4 * 4 + 2] = v.z; sx[c][f4 * 4 + 3] = v.w;
  }
  __syncthreads();
  if (t < 64) {
    float s = 0.f;
    for (int c = 0; c < C_; ++c) { float v = sx[c][t]; s = fmaf(v, v, s); }
    xx[b * N_ + n0 + t] = s;
  }
  for (int u = t; u < 64 * 16; u += 256) {
    int n = u >> 4, cb = u & 15;
    float vv[8]; s16x8 hv;
#pragma unroll
    for (int j = 0; j < 8; ++j) {
      float v = sx[cb * 8 + j][n];
      vv[j] = v;
      hv[j] = (short)__builtin_bit_cast(u16, (__bf16)v);
    }
    size_t ro = ((size_t)b * N_ + n0 + n) * C_;
    *(float4*)&xT32[ro + cb * 8]     = make_float4(vv[0], vv[1], vv[2], vv[3]);
    *(float4*)&xT32[ro + cb * 8 + 4] = make_float4(vv[4], vv[5], vv[6], vv[7]);
    int sc = cb ^ (n & 7);
    *(s16x8*)&xh[ro + sc * 8] = hv;
  }
}

// ============ knn stage 1: bf16 hh MFMA distances -> top-8 candidates/query
//              (branchless packed u32 top-5 per unit) ============
__global__ __launch_bounds__(256) void knn_mfma(const u16* __restrict__ xh,
                                                const float* __restrict__ xx,
                                                int* __restrict__ cand8) {
  __shared__ __align__(16) char smem[40960];  // 2x16KB staging; merge aliases 64x85 u32
  const int b = blockIdx.y, q0 = blockIdx.x * 64;
  const int t = threadIdx.x;
  const int lane = t & 63, wv = t >> 6, lq = t & 15, lh = (t >> 4) & 3;
  const u16* xhb = xh + (size_t)b * N_ * C_;
  const float* xxb = xx + b * N_;

  s16x8 qf[4][4];
#pragma unroll
  for (int qt = 0; qt < 4; ++qt)
#pragma unroll
    for (int ks = 0; ks < 4; ++ks) {
      int q = q0 + qt * 16 + lq;
      int ch = (ks * 4 + lh) ^ (q & 7);
      qf[qt][ks] = *(const s16x8*)&xhb[(size_t)q * C_ + ch * 8];
    }

  u32 pk[4][5];
#pragma unroll
  for (int qt = 0; qt < 4; ++qt)
#pragma unroll
    for (int s = 0; s < 5; ++s) pk[qt][s] = 0xFFFFFFFFu;

  auto stage = [&](int bufi, int m0) {
    const char* s = (const char*)(xhb + (size_t)m0 * C_);
    char* d = smem + bufi * 16384;
#pragma unroll
    for (int c = 0; c < 4; ++c) {
      int off = (wv * 4 + c) * 1024;
      glds16(s + off + lane * 16, d + off);
    }
  };

  stage(0, 0);
  asm volatile("s_waitcnt vmcnt(0)");
  __syncthreads();

  for (int step = 0; step < 32; ++step) {
    const int cur = step & 1;
    if (step < 31) stage(cur ^ 1, (step + 1) * 64);
    const char* mb = smem + cur * 16384;
    f32x4 acc[4];
#pragma unroll
    for (int qt = 0; qt < 4; ++qt) acc[qt] = (f32x4){0.f, 0.f, 0.f, 0.f};
#pragma unroll
    for (int ks = 0; ks < 4; ++ks) {
      int row = wv * 16 + lq;
      int ch = (ks * 4 + lh) ^ (lq & 7);
      s16x8 mf = *(const s16x8*)(mb + row * 256 + ch * 16);
#pragma unroll
      for (int qt = 0; qt < 4; ++qt)
        acc[qt] = __builtin_amdgcn_mfma_f32_16x16x32_bf16(mf, qf[qt][ks], acc[qt], 0, 0, 0);
    }
    const int mrow = step * 64 + wv * 16 + lh * 4;
    float4 xm4 = *(const float4*)&xxb[mrow];
    float xma[4] = {xm4.x, xm4.y, xm4.z, xm4.w};
#pragma unroll
    for (int r = 0; r < 4; ++r) {
#pragma unroll
      for (int qt = 0; qt < 4; ++qt) {
        float dd = fmaf(acc[qt][r], -2.f, xma[r]);
        u32 s = __builtin_bit_cast(u32, dd);
        u32 neg = (u32)((int)s >> 31);
        u32 u = s ^ (neg | 0x80000000u);
        u32 v = (u & 0xFFFFF800u) | (u32)(mrow + r);
#pragma unroll
        for (int s5 = 0; s5 < 5; ++s5) {
          u32 lo = umin32(v, pk[qt][s5]);
          v = umax32(v, pk[qt][s5]);
          pk[qt][s5] = lo;
        }
      }
    }
    asm volatile("s_waitcnt vmcnt(0)");
    __syncthreads();
  }

  u32* cd = (u32*)smem;
  const int unit = wv * 4 + lh;
#pragma unroll
  for (int qt = 0; qt < 4; ++qt) {
    int ql = qt * 16 + lq;
#pragma unroll
    for (int s = 0; s < 5; ++s) cd[ql * 85 + unit * 5 + s] = pk[qt][s];
  }
  __syncthreads();
  if (t < 64) {
    u32 fd[8];
#pragma unroll
    for (int s = 0; s < 8; ++s) fd[s] = 0xFFFFFFFFu;
    for (int j = 0; j < 80; ++j) {
      u32 v = cd[t * 85 + j];
#pragma unroll
      for (int s = 0; s < 8; ++s) {
        u32 lo = umin32(v, fd[s]);
        v = umax32(v, fd[s]);
        fd[s] = lo;
      }
    }
#pragma unroll
    for (int s = 0; s < 8; ++s)
      cand8[((size_t)b * N_ + q0 + t) * 8 + s] = (int)(fd[s] & 0x7FFu);
  }
}

// ============ knn stage 2: exact fp32 rerank of 8 candidates -> top-4 ============
__global__ __launch_bounds__(256) void rerank_kernel(const float* __restrict__ xT32,
                                                     const float* __restrict__ xx,
                                                     const int* __restrict__ cand8,
                                                     int* __restrict__ knn_out) {
  __shared__ __align__(16) float sq[64][132];
  __shared__ float sd[64][8];
  __shared__ int   si[64][8];
  const int b = blockIdx.y, n0 = blockIdx.x * 64;
  const int t = threadIdx.x;
  const float* xb32 = xT32 + (size_t)b * N_ * C_;
  for (int u = t; u < 64 * 32; u += 256) {
    int n = u >> 5, seg = u & 31;
    *(float4*)&sq[n][seg * 4] = *(const float4*)&xb32[(size_t)(n0 + n) * C_ + seg * 4];
  }
  __syncthreads();
  const int ql = t >> 2, cs = t & 3;
#pragma unroll
  for (int cc = 0; cc < 2; ++cc) {
    int cslot = cs + cc * 4;
    int idx = cand8[((size_t)b * N_ + n0 + ql) * 8 + cslot];
    const float* mr = &xb32[(size_t)idx * C_];
    float a0 = 0.f, a1 = 0.f, a2 = 0.f, a3 = 0.f;
#pragma unroll 8
    for (int i = 0; i < 32; ++i) {
      float4 qv = *(const float4*)&sq[ql][i * 4];
      float4 mv = *(const float4*)&mr[i * 4];
      a0 = fmaf(qv.x, mv.x, a0); a1 = fmaf(qv.y, mv.y, a1);
      a2 = fmaf(qv.z, mv.z, a2); a3 = fmaf(qv.w, mv.w, a3);
    }
    float dot = (a0 + a1) + (a2 + a3);
    sd[ql][cslot] = xx[(size_t)b * N_ + idx] - 2.f * dot;
    si[ql][cslot] = idx;
  }
  __syncthreads();
  if (t < 64) {
    float dloc[8]; int iloc[8];
#pragma unroll
    for (int j = 0; j < 8; ++j) { dloc[j] = sd[t][j]; iloc[j] = si[t][j]; }
    u32 used = 0;
#pragma unroll
    for (int s = 0; s < 4; ++s) {
      float bdv = 1e30f; int bidx = 0x7fffffff; int bj = 0;
#pragma unroll
      for (int j = 0; j < 8; ++j) {
        if (!((used >> j) & 1)) {
          bool bet = (dloc[j] < bdv) || (dloc[j] == bdv && iloc[j] < bidx);
          if (bet) { bdv = dloc[j]; bidx = iloc[j]; bj = j; }
        }
      }
      used |= 1u << bj;
      knn_out[((size_t)b * N_ + n0 + t) * K_ + s] = bidx;
    }
  }
}

// ============ fallback kernels (used only if ws too small) ============
__global__ __launch_bounds__(256) void xx_kernel(const float* __restrict__ x,
                                                 float* __restrict__ xx) {
  int g = blockIdx.x * 256 + threadIdx.x;
  int b = g >> 11;
  int n = g & (N_ - 1);
  const float* xp = x + (size_t)b * C_ * N_ + n;
  float s = 0.f;
#pragma unroll 8
  for (int c = 0; c < C_; ++c) { float v = xp[(size_t)c * N_]; s += v * v; }
  xx[g] = s;
}

__global__ __launch_bounds__(256) void knn_kernel(const float* __restrict__ x,
                                                  const float* __restrict__ xx,
                                                  int* __restrict__ knn_out) {
  __shared__ __align__(16) float qT[C_ * 64];
  __shared__ __align__(16) float mT[C_ * 64];
  const int b = blockIdx.y;
  const int q0 = blockIdx.x * 64;
  const int t = threadIdx.x;
  const float* xb = x + (size_t)b * C_ * N_;
  const float* xxb = xx + b * N_;
  for (int i = t; i < C_ * 64; i += 256) {
    int c = i >> 6, q = i & 63;
    qT[i] = xb[(size_t)c * N_ + q0 + q];
  }
  const int tq = t & 15;
  const int tm = t >> 4;
  float bd[4][4]; int bi[4][4];
#pragma unroll
  for (int a = 0; a < 4; ++a)
#pragma unroll
    for (int s = 0; s < 4; ++s) { bd[a][s] = 1e30f; bi[a][s] = 0; }
  for (int m0 = 0; m0 < N_; m0 += 64) {
    __syncthreads();
    for (int i = t; i < C_ * 64; i += 256) {
      int c = i >> 6, m = i & 63;
      mT[i] = xb[(size_t)c * N_ + m0 + m];
    }
    __syncthreads();
    float acc[4][4];
#pragma unroll
    for (int a = 0; a < 4; ++a)
#pragma unroll
      for (int j = 0; j < 4; ++j) acc[a][j] = 0.f;
#pragma unroll 4
    for (int c = 0; c < C_; ++c) {
      float4 qv = *(const float4*)&qT[c * 64 + tq * 4];
      float4 mv = *(const float4*)&mT[c * 64 + tm * 4];
      float qa[4] = {qv.x, qv.y, qv.z, qv.w};
      float ma[4] = {mv.x, mv.y, mv.z, mv.w};
#pragma unroll
      for (int a = 0; a < 4; ++a)
#pragma unroll
        for (int j = 0; j < 4; ++j) acc[a][j] += qa[a] * ma[j];
    }
#pragma unroll
    for (int j = 0; j < 4; ++j) {
      float xm = xxb[m0 + tm * 4 + j];
      int id = m0 + tm * 4 + j;
#pragma unroll
      for (int a = 0; a < 4; ++a) {
        float d = xm - 2.f * acc[a][j];
        if (d < bd[a][3]) {
          bd[a][3] = d; bi[a][3] = id;
#pragma unroll
          for (int s = 3; s > 0; --s)
            if (bd[a][s] < bd[a][s - 1]) {
              float td = bd[a][s]; bd[a][s] = bd[a][s - 1]; bd[a][s - 1] = td;
              int ti = bi[a][s]; bi[a][s] = bi[a][s - 1]; bi[a][s - 1] = ti;
            }
        }
      }
    }
  }
  __syncthreads();
  float* cd = qT;
  int* ci = (int*)mT;
#pragma unroll
  for (int a = 0; a < 4; ++a) {
    int q = tq * 4 + a;
#pragma unroll
    for (int s = 0; s < 4; ++s) {
      cd[q * 64 + tm * 4 + s] = bd[a][s];
      ci[q * 64 + tm * 4 + s] = bi[a][s];
    }
  }
  __syncthreads();
  if (t < 64) {
    float fd[4]; int fi[4];
#pragma unroll
    for (int s = 0; s < 4; ++s) { fd[s] = 1e30f; fi[s] = 0; }
    for (int j = 0; j < 64; ++j) {
      float d = cd[t * 64 + j];
      int id = ci[t * 64 + j];
      if (d < fd[3]) {
        fd[3] = d; fi[3] = id;
#pragma unroll
        for (int s = 3; s > 0; --s)
          if (fd[s] < fd[s - 1]) {
            float td = fd[s]; fd[s] = fd[s - 1]; fd[s - 1] = td;
            int ti = fi[s]; fi[s] = fi[s - 1]; fi[s - 1] = ti;
          }
      }
    }
#pragma unroll
    for (int s = 0; s < 4; ++s)
      knn_out[(b * N_ + q0 + t) * K_ + s] = fi[s];
  }
}

// ============ fused: gather + e1 + e2 + e3 + max, bf16 MFMA ============
// LDS carve (bytes, total 30976 -> 5 blocks/CU):
//   cT  @0      [16][136] bf16 (4352B)
//   e1T @4352   [64][72]  bf16 (9216B)   -- aliased by oSt [64][36] f32 after p2
//   nT  @13568  [64][136] bf16 (17408B)  -- aliased by e2T after p2 MFMAs
// Barriers: B1 post-stage, B2 post-e1T, B3 post-p2-mfma, B4 post-e2T, B5 post-oSt
__global__ __launch_bounds__(256, 5) void fused_mfma(
    const float* __restrict__ x, const u16* __restrict__ xh,
    const u16* __restrict__ wh, const int* __restrict__ knn_idx,
    const float* __restrict__ w1, const float* __restrict__ b1,
    const float* __restrict__ w2, const float* __restrict__ b2,
    const float* __restrict__ w3, const float* __restrict__ b3,
    float* __restrict__ out) {
  __shared__ __align__(16) char fsm[30976];
  __bf16 (*cT)[136]  = (__bf16(*)[136])(fsm);
  __bf16 (*e1T)[72]  = (__bf16(*)[72])(fsm + 4352);
  float  (*oSt)[36]  = (float(*)[36])(fsm + 4352);
  __bf16 (*nT)[136]  = (__bf16(*)[136])(fsm + 13568);
  __bf16 (*e2T)[136] = (__bf16(*)[136])(fsm + 13568);

  const int b  = blockIdx.y;
  const int n0 = blockIdx.x * 16;
  const int t  = threadIdx.x;
  const float* xb = x + (size_t)b * C_ * N_;
  const u16* xhb = xh ? xh + (size_t)b * N_ * C_ : nullptr;
  const u16* w1h = wh;            // [64][256]
  const u16* w2h = wh + 16384;    // [128][320]
  const u16* w3h = wh + 57344;    // [64][64]

  // ---- stage (no nidx LDS: direct per-thread gathers, broadcast-coalesced) ----
  {
    const int stn = t >> 4, stc = t & 15;
    const int kbase = (b * N_ + n0) * K_;
    if (xhb) {
      int gn = n0 + stn;
      *(s16x8*)&cT[stn][stc * 8] =
          *(const s16x8*)&xhb[(size_t)gn * C_ + ((stc ^ (gn & 7)) * 8)];
#pragma unroll
      for (int it = 0; it < 4; ++it) {
        int col = stn + 16 * it;
        int nid = knn_idx[kbase + col];
        *(s16x8*)&nT[col][stc * 8] =
            *(const s16x8*)&xhb[(size_t)nid * C_ + ((stc ^ (nid & 7)) * 8)];
      }
    } else {
      const float* srcc = xb + (size_t)(stc * 8) * N_ + n0 + stn;
      bf16x8 raw;
#pragma unroll
      for (int j = 0; j < 8; ++j) raw[j] = (__bf16)srcc[(size_t)j * N_];
      *(bf16x8*)&cT[stn][stc * 8] = raw;
#pragma unroll
      for (int it = 0; it < 4; ++it) {
        int col = stn + 16 * it;
        int nid = knn_idx[kbase + col];
        const float* src = xb + (size_t)(stc * 8) * N_ + nid;
        bf16x8 rw;
#pragma unroll
        for (int j = 0; j < 8; ++j) rw[j] = (__bf16)src[(size_t)j * N_];
        *(bf16x8*)&nT[col][stc * 8] = rw;
      }
    }
  }
  __syncthreads();   // B1

  const int lq = t & 15;
  const int lh = (t >> 4) & 3;
  const int wv = t >> 6;

  // ---- phase 1: e1 = relu(w1 @ f + b1), K=256 (raw f) ----
  {
    const u16* w1hr = w1h + (size_t)(wv * 16 + lq) * C2_;
    const float* w1r = w1 + (size_t)(wv * 16 + lq) * C2_;
    f32x4 acc[4];
#pragma unroll
    for (int cg = 0; cg < 4; ++cg) acc[cg] = (f32x4){0.f, 0.f, 0.f, 0.f};
#pragma unroll
    for (int ks = 0; ks < 8; ++ks) {
      s16x8 a = wh ? *(const s16x8*)&w1hr[ks * 32 + lh * 8]
                   : ldw_bf16(w1r + ks * 32 + lh * 8);
#pragma unroll
      for (int cg = 0; cg < 4; ++cg) {
        const __bf16* bp = (ks < 4)
            ? &cT[cg * 4 + (lq >> 2)][ks * 32 + lh * 8]
            : &nT[cg * 16 + lq][(ks - 4) * 32 + lh * 8];
        acc[cg] = __builtin_amdgcn_mfma_f32_16x16x32_bf16(
            a, *(const s16x8*)bp, acc[cg], 0, 0, 0);
      }
    }
#pragma unroll
    for (int cg = 0; cg < 4; ++cg) {
      bf16x4 st;
#pragma unroll
      for (int r = 0; r < 4; ++r) {
        float v = acc[cg][r] + b1[wv * 16 + lh * 4 + r];
        st[r] = (__bf16)fmaxf(v, 0.f);
      }
      *(bf16x4*)&e1T[cg * 16 + lq][wv * 16 + lh * 4] = st;
    }
  }
  __syncthreads();   // B2

  // ---- phase 2: e2 = relu(w2 @ [relu(e1); relu(f)] + b2), K=320 ----
  // relu(f) applied in registers at read time (bit-exact); acc held across B3.
  f32x4 acc2[2][4];
  {
    const u16* w2hr0 = w2h + (size_t)(wv * 32 + lq) * ED_;
    const u16* w2hr1 = w2hr0 + (size_t)16 * ED_;
    const float* w2r0 = w2 + (size_t)(wv * 32 + lq) * ED_;
    const float* w2r1 = w2r0 + (size_t)16 * ED_;
#pragma unroll
    for (int ro = 0; ro < 2; ++ro)
#pragma unroll
      for (int cg = 0; cg < 4; ++cg) acc2[ro][cg] = (f32x4){0.f, 0.f, 0.f, 0.f};
#pragma unroll
    for (int ks = 0; ks < 10; ++ks) {
      s16x8 a0 = wh ? *(const s16x8*)&w2hr0[ks * 32 + lh * 8]
                    : ldw_bf16(w2r0 + ks * 32 + lh * 8);
      s16x8 a1 = wh ? *(const s16x8*)&w2hr1[ks * 32 + lh * 8]
                    : ldw_bf16(w2r1 + ks * 32 + lh * 8);
#pragma unroll
      for (int cg = 0; cg < 4; ++cg) {
        s16x8 bf;
        if (ks < 2)      bf = *(const s16x8*)&e1T[cg * 16 + lq][ks * 32 + lh * 8];
        else if (ks < 6) bf = relu8(*(const s16x8*)&cT[cg * 4 + (lq >> 2)][(ks - 2) * 32 + lh * 8]);
        else             bf = relu8(*(const s16x8*)&nT[cg * 16 + lq][(ks - 6) * 32 + lh * 8]);
        acc2[0][cg] = __builtin_amdgcn_mfma_f32_16x16x32_bf16(a0, bf, acc2[0][cg], 0, 0, 0);
        acc2[1][cg] = __builtin_amdgcn_mfma_f32_16x16x32_bf16(a1, bf, acc2[1][cg], 0, 0, 0);
      }
    }
  }
  __syncthreads();   // B3 (all reads of cT/nT/e1T done; nT region now reusable)
  {
#pragma unroll
    for (int ro = 0; ro < 2; ++ro)
#pragma unroll
      for (int cg = 0; cg < 4; ++cg) {
        bf16x4 st;
#pragma unroll
        for (int r = 0; r < 4; ++r) {
          float v = acc2[ro][cg][r] + b2[wv * 32 + ro * 16 + lh * 4 + r];
          st[r] = (__bf16)fmaxf(v, 0.f);
        }
        *(bf16x4*)&e2T[cg * 16 + lq][wv * 32 + ro * 16 + lh * 4] = st;
      }
  }
  __syncthreads();   // B4

  // ---- phase 3: e3 = w3 @ e2' (K=64), max over k, +b3 -> oSt (e1T region) ----
  {
    s16x8 a0, a1;
    if (wh) {
      const u16* w3hr = w3h + (size_t)(wv * 16 + lq) * O_;
      a0 = *(const s16x8*)&w3hr[lh * 8];
      a1 = *(const s16x8*)&w3hr[32 + lh * 8];
    } else {
      const float* w3r = w3 + (size_t)(wv * 16 + lq) * O_;
      a0 = ldw_bf16(w3r + lh * 8);
      a1 = ldw_bf16(w3r + 32 + lh * 8);
    }
#pragma unroll
    for (int cg = 0; cg < 8; ++cg) {
      int col = cg * 16 + lq;
      int nl = col >> 3, rr = (col >> 2) & 1, kk = col & 3;
      const __bf16* base = &e2T[nl * 4 + kk][rr * 64];
      f32x4 acc = {0.f, 0.f, 0.f, 0.f};
      acc = __builtin_amdgcn_mfma_f32_16x16x32_bf16(a0, *(const s16x8*)(base + lh * 8),      acc, 0, 0, 0);
      acc = __builtin_amdgcn_mfma_f32_16x16x32_bf16(a1, *(const s16x8*)(base + 32 + lh * 8), acc, 0, 0, 0);
      float vv[4];
#pragma unroll
      for (int r = 0; r < 4; ++r) {
        float v = acc[r];
        v = fmaxf(v, __shfl_xor(v, 1));
        v = fmaxf(v, __shfl_xor(v, 2));
        vv[r] = v;
      }
      if ((lq & 3) == 0) {
        int mloc = col >> 2;
        int o = wv * 16 + lh * 4;
#pragma unroll
        for (int r = 0; r < 4; ++r) oSt[o + r][mloc] = vv[r] + b3[o + r];
      }
    }
  }
  __syncthreads();   // B5

#pragma unroll
  for (int it = 0; it < 2; ++it) {
    int u = t + it * 256;
    int o = u >> 3, seg = u & 7;
    *(float4*)&out[((size_t)b * O_ + o) * NM_ + n0 * 2 + seg * 4] =
        *(const float4*)&oSt[o][seg * 4];
  }
}

extern "C" void kernel_launch(void* const* d_in, const int* in_sizes, int n_in,
                              void* d_out, int out_size, void* d_ws, size_t ws_size,
                              hipStream_t stream) {
  const float* x  = (const float*)d_in[0];
  const float* w1 = (const float*)d_in[1];
  const float* b1 = (const float*)d_in[2];
  const float* w2 = (const float*)d_in[3];
  const float* b2 = (const float*)d_in[4];
  const float* w3 = (const float*)d_in[5];
  const float* b3 = (const float*)d_in[6];
  float* out = (float*)d_out;

  const size_t off_xh   = (size_t)B_ * N_ * C_ * 4;                 // 16 MB
  const size_t off_xx   = off_xh + (size_t)B_ * N_ * C_ * 2;        // +8 MB
  const size_t off_c8   = off_xx + (size_t)B_ * N_ * 4;             // +128 KB
  const size_t off_knn  = off_c8 + (size_t)B_ * N_ * 8 * 4;         // +1 MB
  const size_t off_wh   = off_knn + (size_t)B_ * N_ * K_ * 4;       // +512 KB
  const size_t NEED     = off_wh + (size_t)61440 * 2;               // +120 KB

  if (ws_size >= NEED) {
    float* xT32 = (float*)d_ws;
    u16*   xhp  = (u16*)((char*)d_ws + off_xh);
    float* xx   = (float*)((char*)d_ws + off_xx);
    int*   c8   = (int*)((char*)d_ws + off_c8);
    int*   knn  = (int*)((char*)d_ws + off_knn);
    u16*   whp  = (u16*)((char*)d_ws + off_wh);

    hipLaunchKernelGGL(prep_kernel, dim3(N_ / 64, B_ + 1), dim3(256), 0, stream,
                       x, w1, w2, w3, xT32, xhp, xx, whp);
    hipLaunchKernelGGL(knn_mfma, dim3(N_ / 64, B_), dim3(256), 0, stream, xhp, xx, c8);
    hipLaunchKernelGGL(rerank_kernel, dim3(N_ / 64, B_), dim3(256), 0, stream, xT32, xx, c8, knn);
    hipLaunchKernelGGL(fused_mfma, dim3(N_ / 16, B_), dim3(256), 0, stream,
                       x, xhp, whp, knn, w1, b1, w2, b2, w3, b3, out);
  } else {
    float* xx = (float*)d_ws;
    int* knn = (int*)((char*)d_ws + (size_t)B_ * N_ * 4);
    hipLaunchKernelGGL(xx_kernel, dim3((B_ * N_) / 256), dim3(256), 0, stream, x, xx);
    hipLaunchKernelGGL(knn_kernel, dim3(N_ / 64, B_), dim3(256), 0, stream, x, xx, knn);
    hipLaunchKernelGGL(fused_mfma, dim3(N_ / 16, B_), dim3(256), 0, stream,
                       x, (const u16*)nullptr, (const u16*)nullptr, knn,
                       w1, b1, w2, b2, w3, b3, out);
  }
}